// Round 8
// baseline (2683.962 us; speedup 1.0000x reference)
//
#include <hip/hip_runtime.h>

// GNODecoder round 8: r7's 1024-thread block worked (2.0 ms) but the
// allocator picked 64 VGPR (it can't see the 152.8 KB dynamic LDS, assumed
// 8 waves/EU possible) and spilled h0/h1 -> 2.3 GB scratch traffic.
// Fix 1: amdgpu_waves_per_eu(4,4) on fused_kernel -> budget 128 VGPR
//        (LDS already caps at 1 block/CU = 4 waves/EU; nothing lost).
// Fix 2: proj_kernel had the round-3 disease (P0 via s_load thrashing the
//        16 KB scalar cache). New 512-thread proj stages P0/pb0/P1 in
//        136 KB LDS (launch_bounds(512,2) -> 256-VGPR budget, a[128] in regs).

#define BLOCK 1024
#define NW    16   // waves per block

// LDS float offsets (round-4 proven layout)
#define OFF_W0   0      // [6*64]
#define OFF_B0   384    // [64]
#define OFF_W1   448    // [64*64]
#define OFF_B1   4544   // [64]
#define OFF_W2   4608   // [64*128]
#define OFF_B2   12800  // [128]
#define OFF_SACC 12928  // [QB*129]

__device__ __forceinline__ float gelu_f(float x) {
    // jax.nn.gelu default (approximate=True, tanh form)
    float x3 = x * x * x;
    float t  = 0.7978845608028654f * fmaf(0.044715f, x3, x);
    float e  = __expf(2.0f * t);
    float r  = __builtin_amdgcn_rcpf(e + 1.0f);
    return 0.5f * x * (1.0f + (1.0f - 2.0f * r));
}

// ---------- sort machinery (proven) ----------

__global__ void hist_kernel(const int* __restrict__ dst, int* __restrict__ hist, int E) {
    int e = blockIdx.x * blockDim.x + threadIdx.x;
    if (e < E) atomicAdd(&hist[dst[e]], 1);
}

__global__ __launch_bounds__(1024) void scan_kernel(const int* __restrict__ hist,
                                                    int* __restrict__ start, int n) {
    __shared__ int wsum[16];
    __shared__ int woff[16];
    int tid = threadIdx.x;
    int lane = tid & 63, wid = tid >> 6;
    int carry = 0;  // meaningful on tid 0 only
    for (int base = 0; base < n; base += 1024) {
        int i = base + tid;
        int v = (i < n) ? hist[i] : 0;
        int incl = v;
#pragma unroll
        for (int off = 1; off < 64; off <<= 1) {
            int t = __shfl_up(incl, off, 64);
            if (lane >= off) incl += t;
        }
        if (lane == 63) wsum[wid] = incl;
        __syncthreads();
        if (tid == 0) {
            int acc = carry;
#pragma unroll
            for (int w = 0; w < 16; ++w) { woff[w] = acc; acc += wsum[w]; }
            carry = acc;
        }
        __syncthreads();
        if (i < n) start[i] = woff[wid] + incl - v;
        __syncthreads();
    }
    if (threadIdx.x == 0) start[n] = carry;
}

__global__ void scatter_kernel(const int* __restrict__ dst, const int* __restrict__ src,
                               const int* __restrict__ start, int* __restrict__ cursor,
                               int* __restrict__ dsts, int* __restrict__ srcs, int E) {
    int e = blockIdx.x * blockDim.x + threadIdx.x;
    if (e >= E) return;
    int d = dst[e];
    int pos = start[d] + atomicAdd(&cursor[d], 1);
    dsts[pos] = d;
    srcs[pos] = src[e];
}

// ---------- fused: round-4 per-edge body, 16-wave block, shared sacc ----------

template <int QB, bool FUSED_PROJ>
__global__ __launch_bounds__(BLOCK)
__attribute__((amdgpu_waves_per_eu(4, 4)))
void fused_kernel(
    const float* __restrict__ rndata,   // [NL,128]
    const float* __restrict__ qpos,     // [NQ,3]
    const float* __restrict__ lpos,     // [NL,3]
    const int*   __restrict__ dsts,     // [E] sorted by dst
    const int*   __restrict__ srcs,     // [E]
    const int*   __restrict__ start,    // [NQ+1]
    const float* __restrict__ W0, const float* __restrict__ b0,
    const float* __restrict__ W1, const float* __restrict__ b1,
    const float* __restrict__ W2, const float* __restrict__ b2,
    const float* __restrict__ P0, const float* __restrict__ pb0,
    const float* __restrict__ P1, const float* __restrict__ pb1,
    float* __restrict__ agg,            // [NQ,128] mean (path A)
    float* __restrict__ out,            // [NQ,4]   (FUSED_PROJ)
    int nq)
{
    extern __shared__ float smem[];
    int tid = threadIdx.x;

    // ---- stage weights (one copy per 16-wave block) ----
    ((float4*)(smem + OFF_W1))[tid] = ((const float4*)W1)[tid];            // 1024 f4
    ((float4*)(smem + OFF_W2))[tid]        = ((const float4*)W2)[tid];     // 2048 f4
    ((float4*)(smem + OFF_W2))[tid + 1024] = ((const float4*)W2)[tid + 1024];
    if (tid < 96)       ((float4*)(smem + OFF_W0))[tid]       = ((const float4*)W0)[tid];
    else if (tid < 112) ((float4*)(smem + OFF_B0))[tid - 96]  = ((const float4*)b0)[tid - 96];
    else if (tid < 128) ((float4*)(smem + OFF_B1))[tid - 112] = ((const float4*)b1)[tid - 112];
    else if (tid < 160) ((float4*)(smem + OFF_B2))[tid - 128] = ((const float4*)b2)[tid - 128];
    for (int i = tid; i < QB * 129; i += BLOCK) smem[OFF_SACC + i] = 0.f;
    __syncthreads();

    const float* sw0 = smem + OFF_W0;
    const float* sb0 = smem + OFF_B0;
    const float* sw1 = smem + OFF_W1;
    const float* sb1 = smem + OFF_B1;
    const float* sw2 = smem + OFF_W2;
    const float* sb2 = smem + OFF_B2;
    float*       sacc = smem + OFF_SACC;   // stride 129

    int w = tid >> 6, lane = tid & 63;
    int q0   = blockIdx.x * QB;
    int qend = min(q0 + QB, nq);
    int e0 = start[q0], e1 = start[qend];

    for (int base = e0 + w * 64; base < e1; base += NW * 64) {
        int  e     = base + lane;
        bool valid = (e < e1);
        int  d = valid ? dsts[e] : q0;
        int  s = valid ? srcs[e] : 0;
        int  ql = d - q0;

        float q0c = qpos[d * 3 + 0], q1c = qpos[d * 3 + 1], q2c = qpos[d * 3 + 2];
        float l0c = lpos[s * 3 + 0], l1c = lpos[s * 3 + 1], l2c = lpos[s * 3 + 2];

        // layer 0: [6] -> [64], gelu
        float h0[64];
#pragma unroll
        for (int j = 0; j < 64; ++j) {
            float a = sb0[j];
            a = fmaf(q0c, sw0[0 * 64 + j], a);
            a = fmaf(q1c, sw0[1 * 64 + j], a);
            a = fmaf(q2c, sw0[2 * 64 + j], a);
            a = fmaf(l0c, sw0[3 * 64 + j], a);
            a = fmaf(l1c, sw0[4 * 64 + j], a);
            a = fmaf(l2c, sw0[5 * 64 + j], a);
            h0[j] = gelu_f(a);
        }

        // layer 1: [64] -> [64], gelu
        float h1[64];
#pragma unroll
        for (int jj = 0; jj < 64; jj += 8) {
            float acc[8];
#pragma unroll
            for (int u = 0; u < 8; ++u) acc[u] = sb1[jj + u];
#pragma unroll
            for (int i2 = 0; i2 < 64; ++i2) {
                float h = h0[i2];
#pragma unroll
                for (int u = 0; u < 8; ++u)
                    acc[u] = fmaf(h, sw1[i2 * 64 + jj + u], acc[u]);
            }
#pragma unroll
            for (int u = 0; u < 8; ++u) h1[jj + u] = gelu_f(acc[u]);
        }

        // layer 2: [64] -> [128], * rndata[src], LDS per-query accumulate
        const float4* r4   = (const float4*)(rndata + (size_t)s * 128);
        float*        aacc = &sacc[ql * 129];
#pragma unroll 1
        for (int jj = 0; jj < 128; jj += 8) {
            float acc[8];
#pragma unroll
            for (int u = 0; u < 8; ++u) acc[u] = sb2[jj + u];
#pragma unroll
            for (int i2 = 0; i2 < 64; ++i2) {
                float h = h1[i2];
#pragma unroll
                for (int u = 0; u < 8; ++u)
                    acc[u] = fmaf(h, sw2[i2 * 128 + jj + u], acc[u]);
            }
            float4 ra = r4[jj / 4], rb = r4[jj / 4 + 1];
            if (valid) {
                atomicAdd(&aacc[jj + 0], acc[0] * ra.x);
                atomicAdd(&aacc[jj + 1], acc[1] * ra.y);
                atomicAdd(&aacc[jj + 2], acc[2] * ra.z);
                atomicAdd(&aacc[jj + 3], acc[3] * ra.w);
                atomicAdd(&aacc[jj + 4], acc[4] * rb.x);
                atomicAdd(&aacc[jj + 5], acc[5] * rb.y);
                atomicAdd(&aacc[jj + 6], acc[6] * rb.z);
                atomicAdd(&aacc[jj + 7], acc[7] * rb.w);
            }
        }
    }
    __syncthreads();

    if (!FUSED_PROJ) {
        // write per-query mean to global agg (coalesced across c)
        for (int idx = tid; idx < QB * 128; idx += BLOCK) {
            int ql = idx >> 7, c = idx & 127;
            int q  = q0 + ql;
            if (q < qend) {
                float deg = (float)(start[q + 1] - start[q]);
                agg[(size_t)q * 128 + c] = sacc[ql * 129 + c] / fmaxf(deg, 1.f);
            }
        }
    } else {
        if (tid < QB) {
            int q = q0 + tid;
            if (q < nq) {
                float deg = (float)(start[q + 1] - start[q]);
                float inv = 1.0f / fmaxf(deg, 1.f);
                const float* aq = &sacc[tid * 129];
                float o0 = pb1[0], o1 = pb1[1], o2 = pb1[2], o3 = pb1[3];
#pragma unroll 1
                for (int jj = 0; jj < 256; jj += 8) {
                    float acc[8];
#pragma unroll
                    for (int u = 0; u < 8; ++u) acc[u] = pb0[jj + u];
#pragma unroll
                    for (int i = 0; i < 128; ++i) {
                        float av = aq[i] * inv;
#pragma unroll
                        for (int u = 0; u < 8; ++u)
                            acc[u] = fmaf(av, P0[i * 256 + jj + u], acc[u]);
                    }
#pragma unroll
                    for (int u = 0; u < 8; ++u) {
                        float h = gelu_f(acc[u]);
                        o0 = fmaf(h, P1[(jj + u) * 4 + 0], o0);
                        o1 = fmaf(h, P1[(jj + u) * 4 + 1], o1);
                        o2 = fmaf(h, P1[(jj + u) * 4 + 2], o2);
                        o3 = fmaf(h, P1[(jj + u) * 4 + 3], o3);
                    }
                }
                float4* o4 = (float4*)(out + (size_t)q * 4);
                *o4 = make_float4(o0, o1, o2, o3);
            }
        }
    }
}

// ---------- projection, LDS-staged weights ----------
// LDS f4 layout: P0 [0,8192) | pb0 [8192,8256) | P1 [8256,8512) | pb1 [8512,8513)
#define PROJ_SMEM_BYTES (8513 * 16)

__global__ __launch_bounds__(512, 2) void proj_lds_kernel(
    const float* __restrict__ agg,      // [NQ,128] mean
    const float* __restrict__ P0, const float* __restrict__ pb0,
    const float* __restrict__ P1, const float* __restrict__ pb1,
    float* __restrict__ out, int nq)
{
    extern __shared__ float smem[];
    {
        float4* s4 = (float4*)smem;
        const float4* g0 = (const float4*)P0;
        for (int i = threadIdx.x; i < 8192; i += 512) s4[i] = g0[i];
        if (threadIdx.x < 64)       s4[8192 + threadIdx.x] = ((const float4*)pb0)[threadIdx.x];
        else if (threadIdx.x < 320) s4[8256 + threadIdx.x - 64] = ((const float4*)P1)[threadIdx.x - 64];
        else if (threadIdx.x == 320) s4[8512] = ((const float4*)pb1)[0];
    }
    __syncthreads();

    const float* sp0  = smem;              // [128*256]
    const float* spb0 = smem + 32768;      // [256]
    const float* sp1  = smem + 33024;      // [256*4]
    const float* spb1 = smem + 34048;      // [4]

    int q = blockIdx.x * blockDim.x + threadIdx.x;
    if (q >= nq) return;

    float a[128];
    const float4* ag4 = (const float4*)(agg + (size_t)q * 128);
#pragma unroll
    for (int i = 0; i < 32; ++i) {
        float4 v = ag4[i];
        a[4 * i + 0] = v.x; a[4 * i + 1] = v.y;
        a[4 * i + 2] = v.z; a[4 * i + 3] = v.w;
    }

    float o0 = spb1[0], o1 = spb1[1], o2 = spb1[2], o3 = spb1[3];
#pragma unroll 1
    for (int jj = 0; jj < 256; jj += 8) {
        float acc[8];
#pragma unroll
        for (int u = 0; u < 8; ++u) acc[u] = spb0[jj + u];
#pragma unroll
        for (int i = 0; i < 128; ++i) {
            float av = a[i];
#pragma unroll
            for (int u = 0; u < 8; ++u)
                acc[u] = fmaf(av, sp0[i * 256 + jj + u], acc[u]);
        }
#pragma unroll
        for (int u = 0; u < 8; ++u) {
            float h = gelu_f(acc[u]);
            o0 = fmaf(h, sp1[(jj + u) * 4 + 0], o0);
            o1 = fmaf(h, sp1[(jj + u) * 4 + 1], o1);
            o2 = fmaf(h, sp1[(jj + u) * 4 + 2], o2);
            o3 = fmaf(h, sp1[(jj + u) * 4 + 3], o3);
        }
    }
    float4* o4 = (float4*)(out + (size_t)q * 4);
    *o4 = make_float4(o0, o1, o2, o3);
}

// fallback proj (global/s_load weights) if LDS opt-in rejected
__global__ __launch_bounds__(256) void proj_kernel(
    const float* __restrict__ agg,
    const float* __restrict__ P0, const float* __restrict__ pb0,
    const float* __restrict__ P1, const float* __restrict__ pb1,
    float* __restrict__ out, int nq)
{
    int q = blockIdx.x * blockDim.x + threadIdx.x;
    if (q >= nq) return;
    float a[128];
    const float4* ag4 = (const float4*)(agg + (size_t)q * 128);
#pragma unroll
    for (int i = 0; i < 32; ++i) {
        float4 v = ag4[i];
        a[4 * i + 0] = v.x; a[4 * i + 1] = v.y;
        a[4 * i + 2] = v.z; a[4 * i + 3] = v.w;
    }
    float o0 = pb1[0], o1 = pb1[1], o2 = pb1[2], o3 = pb1[3];
#pragma unroll 1
    for (int jj = 0; jj < 256; jj += 8) {
        float acc[8];
#pragma unroll
        for (int u = 0; u < 8; ++u) acc[u] = pb0[jj + u];
#pragma unroll
        for (int i = 0; i < 128; ++i) {
            float av = a[i];
#pragma unroll
            for (int u = 0; u < 8; ++u)
                acc[u] = fmaf(av, P0[i * 256 + jj + u], acc[u]);
        }
#pragma unroll
        for (int u = 0; u < 8; ++u) {
            float h = gelu_f(acc[u]);
            o0 = fmaf(h, P1[(jj + u) * 4 + 0], o0);
            o1 = fmaf(h, P1[(jj + u) * 4 + 1], o1);
            o2 = fmaf(h, P1[(jj + u) * 4 + 2], o2);
            o3 = fmaf(h, P1[(jj + u) * 4 + 3], o3);
        }
    }
    float4* o4 = (float4*)(out + (size_t)q * 4);
    *o4 = make_float4(o0, o1, o2, o3);
}

extern "C" void kernel_launch(void* const* d_in, const int* in_sizes, int n_in,
                              void* d_out, int out_size, void* d_ws, size_t ws_size,
                              hipStream_t stream)
{
    const float* rndata = (const float*)d_in[0];
    const float* qpos   = (const float*)d_in[1];
    const float* lpos   = (const float*)d_in[2];
    const int*   dst    = (const int*)d_in[3];
    const int*   src    = (const int*)d_in[4];
    const float* W0  = (const float*)d_in[5];
    const float* b0  = (const float*)d_in[6];
    const float* W1  = (const float*)d_in[7];
    const float* b1  = (const float*)d_in[8];
    const float* W2  = (const float*)d_in[9];
    const float* b2  = (const float*)d_in[10];
    const float* P0  = (const float*)d_in[11];
    const float* pb0 = (const float*)d_in[12];
    const float* P1  = (const float*)d_in[13];
    const float* pb1 = (const float*)d_in[14];

    int nq = in_sizes[1] / 3;
    int E  = in_sizes[3];

    // ws layout: [agg nq*128 (path A)] [hist] [cursor] [start] [dsts] [srcs]
    size_t agg_bytes  = (size_t)nq * 128 * sizeof(float);
    size_t sort_bytes = 0;
    {
        size_t o = 0;
        o += ((size_t)nq * sizeof(int) + 15) & ~(size_t)15;
        o += ((size_t)nq * sizeof(int) + 15) & ~(size_t)15;
        o += ((size_t)(nq + 1) * sizeof(int) + 15) & ~(size_t)15;
        o += ((size_t)E * sizeof(int) + 15) & ~(size_t)15;
        o += ((size_t)E * sizeof(int) + 15) & ~(size_t)15;
        sort_bytes = o;
    }
    bool path_a = (agg_bytes + sort_bytes) <= ws_size;

    size_t off = path_a ? agg_bytes : 0;
    auto alloc = [&](size_t bytes) {
        void* p = (char*)d_ws + off;
        off += (bytes + 15) & ~(size_t)15;
        return p;
    };
    float* agg   = (float*)d_ws;  // path A only
    int* hist    = (int*)alloc((size_t)nq * sizeof(int));
    int* cursor  = (int*)alloc((size_t)nq * sizeof(int));
    int* start   = (int*)alloc((size_t)(nq + 1) * sizeof(int));
    int* dsts    = (int*)alloc((size_t)E * sizeof(int));
    int* srcs    = (int*)alloc((size_t)E * sizeof(int));

    size_t histpad = ((size_t)nq * sizeof(int) + 15) & ~(size_t)15;
    hipMemsetAsync(hist, 0, 2 * histpad, stream);

    hist_kernel<<<(E + 255) / 256, 256, 0, stream>>>(dst, hist, E);
    scan_kernel<<<1, 1024, 0, stream>>>(hist, start, nq);
    scatter_kernel<<<(E + 255) / 256, 256, 0, stream>>>(dst, src, start, cursor, dsts, srcs, E);

    constexpr int    QB_BIG     = 196;
    constexpr int    QB_SMALL   = 23;
    constexpr size_t SMEM_BIG   = (size_t)(12928 + QB_BIG   * 129) * 4;  // 152,848 B
    constexpr size_t SMEM_SMALL = (size_t)(12928 + QB_SMALL * 129) * 4;  // 63,580 B

    if (path_a) {
        bool big = hipFuncSetAttribute(
            reinterpret_cast<const void*>(&fused_kernel<QB_BIG, false>),
            hipFuncAttributeMaxDynamicSharedMemorySize, (int)SMEM_BIG) == hipSuccess;
        if (big) {
            int nb = (nq + QB_BIG - 1) / QB_BIG;
            fused_kernel<QB_BIG, false><<<nb, BLOCK, SMEM_BIG, stream>>>(
                rndata, qpos, lpos, dsts, srcs, start,
                W0, b0, W1, b1, W2, b2, P0, pb0, P1, pb1, agg, nullptr, nq);
        } else {
            int nb = (nq + QB_SMALL - 1) / QB_SMALL;
            fused_kernel<QB_SMALL, false><<<nb, BLOCK, SMEM_SMALL, stream>>>(
                rndata, qpos, lpos, dsts, srcs, start,
                W0, b0, W1, b1, W2, b2, P0, pb0, P1, pb1, agg, nullptr, nq);
        }
        bool proj_lds = hipFuncSetAttribute(
            reinterpret_cast<const void*>(&proj_lds_kernel),
            hipFuncAttributeMaxDynamicSharedMemorySize, (int)PROJ_SMEM_BYTES) == hipSuccess;
        if (proj_lds) {
            proj_lds_kernel<<<(nq + 511) / 512, 512, PROJ_SMEM_BYTES, stream>>>(
                agg, P0, pb0, P1, pb1, (float*)d_out, nq);
        } else {
            proj_kernel<<<(nq + 255) / 256, 256, 0, stream>>>(
                agg, P0, pb0, P1, pb1, (float*)d_out, nq);
        }
    } else {
        bool big = hipFuncSetAttribute(
            reinterpret_cast<const void*>(&fused_kernel<QB_BIG, true>),
            hipFuncAttributeMaxDynamicSharedMemorySize, (int)SMEM_BIG) == hipSuccess;
        if (big) {
            int nb = (nq + QB_BIG - 1) / QB_BIG;
            fused_kernel<QB_BIG, true><<<nb, BLOCK, SMEM_BIG, stream>>>(
                rndata, qpos, lpos, dsts, srcs, start,
                W0, b0, W1, b1, W2, b2, P0, pb0, P1, pb1, nullptr, (float*)d_out, nq);
        } else {
            int nb = (nq + QB_SMALL - 1) / QB_SMALL;
            fused_kernel<QB_SMALL, true><<<nb, BLOCK, SMEM_SMALL, stream>>>(
                rndata, qpos, lpos, dsts, srcs, start,
                W0, b0, W1, b1, W2, b2, P0, pb0, P1, pb1, nullptr, (float*)d_out, nq);
        }
    }
}

// Round 9
// 2632.987 us; speedup vs baseline: 1.0194x; 1.0194x over previous
//
#include <hip/hip_runtime.h>

// GNODecoder round 9: the allocator hard-caps VGPR at 64 for 1024-thread
// blocks (3 rounds of evidence; attributes ignored) -> h0[64]/h1[64] spilled
// 2.4 GB of scratch = the whole 2 ms. Fix: shrink the body to the budget.
// Streaming-split MLP: h0 never materialized (recomputed per phase, +6%
// FLOPs); h1 processed in two 32-float halves, each half's layer-2 partial
// atomically merged into sacc (ds_add doubles to 256/edge, cheap). Peak live
// ~62 floats -> zero spill at 64 VGPR. Launch shape = r7's proven 16-wave
// block, QB=196, one 52 KB weight copy + 98.9 KB sacc in LDS (153.1 KB).
// proj: revert to r7's plain 256-thread kernel (r8's LDS-proj regressed).

#define BLOCK 1024
#define NW    16   // waves per block

// LDS float offsets
#define OFF_W0T  0      // [64][8] rows {W0[0..5][j], b0[j], pad}
#define OFF_B1   512    // [64]
#define OFF_W1   576    // [64*64] row-major
#define OFF_B2   4672   // [128]
#define OFF_W2   4800   // [64*128] row-major
#define OFF_SACC 12992  // [QB*129]

__device__ __forceinline__ float gelu_f(float x) {
    // jax.nn.gelu default (approximate=True, tanh form)
    float x3 = x * x * x;
    float t  = 0.7978845608028654f * fmaf(0.044715f, x3, x);
    float e  = __expf(2.0f * t);
    float r  = __builtin_amdgcn_rcpf(e + 1.0f);
    return 0.5f * x * (1.0f + (1.0f - 2.0f * r));
}

// ---------- sort machinery (proven) ----------

__global__ void hist_kernel(const int* __restrict__ dst, int* __restrict__ hist, int E) {
    int e = blockIdx.x * blockDim.x + threadIdx.x;
    if (e < E) atomicAdd(&hist[dst[e]], 1);
}

__global__ __launch_bounds__(1024) void scan_kernel(const int* __restrict__ hist,
                                                    int* __restrict__ start, int n) {
    __shared__ int wsum[16];
    __shared__ int woff[16];
    int tid = threadIdx.x;
    int lane = tid & 63, wid = tid >> 6;
    int carry = 0;  // meaningful on tid 0 only
    for (int base = 0; base < n; base += 1024) {
        int i = base + tid;
        int v = (i < n) ? hist[i] : 0;
        int incl = v;
#pragma unroll
        for (int off = 1; off < 64; off <<= 1) {
            int t = __shfl_up(incl, off, 64);
            if (lane >= off) incl += t;
        }
        if (lane == 63) wsum[wid] = incl;
        __syncthreads();
        if (tid == 0) {
            int acc = carry;
#pragma unroll
            for (int w = 0; w < 16; ++w) { woff[w] = acc; acc += wsum[w]; }
            carry = acc;
        }
        __syncthreads();
        if (i < n) start[i] = woff[wid] + incl - v;
        __syncthreads();
    }
    if (threadIdx.x == 0) start[n] = carry;
}

__global__ void scatter_kernel(const int* __restrict__ dst, const int* __restrict__ src,
                               const int* __restrict__ start, int* __restrict__ cursor,
                               int* __restrict__ dsts, int* __restrict__ srcs, int E) {
    int e = blockIdx.x * blockDim.x + threadIdx.x;
    if (e >= E) return;
    int d = dst[e];
    int pos = start[d] + atomicAdd(&cursor[d], 1);
    dsts[pos] = d;
    srcs[pos] = src[e];
}

// ---------- fused: streaming-split per-edge MLP, 16-wave block ----------

template <int QB, bool FUSED_PROJ>
__global__ __launch_bounds__(BLOCK) void fused_kernel(
    const float* __restrict__ rndata,   // [NL,128]
    const float* __restrict__ qpos,     // [NQ,3]
    const float* __restrict__ lpos,     // [NL,3]
    const int*   __restrict__ dsts,     // [E] sorted by dst
    const int*   __restrict__ srcs,     // [E]
    const int*   __restrict__ start,    // [NQ+1]
    const float* __restrict__ W0, const float* __restrict__ b0,
    const float* __restrict__ W1, const float* __restrict__ b1,
    const float* __restrict__ W2, const float* __restrict__ b2,
    const float* __restrict__ P0, const float* __restrict__ pb0,
    const float* __restrict__ P1, const float* __restrict__ pb1,
    float* __restrict__ agg,            // [NQ,128] mean (path A)
    float* __restrict__ out,            // [NQ,4]   (FUSED_PROJ)
    int nq)
{
    extern __shared__ float smem[];
    int tid = threadIdx.x;

    // ---- stage weights (one copy per 16-wave block) ----
    ((float4*)(smem + OFF_W1))[tid] = ((const float4*)W1)[tid];            // 1024 f4
    ((float4*)(smem + OFF_W2))[tid]        = ((const float4*)W2)[tid];     // 2048 f4
    ((float4*)(smem + OFF_W2))[tid + 1024] = ((const float4*)W2)[tid + 1024];
    if (tid < 64) {
        int j = tid;
        float* r = smem + OFF_W0T + j * 8;
        r[0] = W0[0 * 64 + j]; r[1] = W0[1 * 64 + j]; r[2] = W0[2 * 64 + j];
        r[3] = W0[3 * 64 + j]; r[4] = W0[4 * 64 + j]; r[5] = W0[5 * 64 + j];
        r[6] = b0[j];          r[7] = 0.f;
        smem[OFF_B1 + j] = b1[j];
    } else if (tid < 96) {
        ((float4*)(smem + OFF_B2))[tid - 64] = ((const float4*)b2)[tid - 64];
    }
    for (int i = tid; i < QB * 129; i += BLOCK) smem[OFF_SACC + i] = 0.f;
    __syncthreads();

    const float* sw0t = smem + OFF_W0T;
    const float* sb1  = smem + OFF_B1;
    const float* sw1  = smem + OFF_W1;
    const float* sb2  = smem + OFF_B2;
    const float* sw2  = smem + OFF_W2;
    float*       sacc = smem + OFF_SACC;   // stride 129

    int w = tid >> 6, lane = tid & 63;
    int q0   = blockIdx.x * QB;
    int qend = min(q0 + QB, nq);
    int e0 = start[q0], e1 = start[qend];

    for (int base = e0 + w * 64; base < e1; base += NW * 64) {
        int  e     = base + lane;
        bool valid = (e < e1);
        int  d = valid ? dsts[e] : q0;
        int  s = valid ? srcs[e] : 0;
        int  ql = d - q0;

        float p0 = qpos[d * 3 + 0], p1 = qpos[d * 3 + 1], p2 = qpos[d * 3 + 2];
        float p3 = lpos[s * 3 + 0], p4 = lpos[s * 3 + 1], p5 = lpos[s * 3 + 2];

        const float4* r4   = (const float4*)(rndata + (size_t)s * 128);
        float*        aacc = &sacc[ql * 129];

        // two phases, each builds half of h1 (32 floats live, not 128)
#pragma unroll 1
        for (int H = 0; H < 2; ++H) {
            float h1h[32];
            {
                const float4* b1r = (const float4*)(sb1 + H * 32);
#pragma unroll
                for (int k4 = 0; k4 < 8; ++k4) {
                    float4 bv = b1r[k4];
                    h1h[4 * k4 + 0] = bv.x; h1h[4 * k4 + 1] = bv.y;
                    h1h[4 * k4 + 2] = bv.z; h1h[4 * k4 + 3] = bv.w;
                }
            }
            // stream h0_i (recomputed per phase), accumulate into h1 half
#pragma unroll 1
            for (int i = 0; i < 64; ++i) {
                const float4* w0r = (const float4*)(sw0t + i * 8);
                float4 wa = w0r[0], wb = w0r[1];
                float a = wb.z;
                a = fmaf(p0, wa.x, a);
                a = fmaf(p1, wa.y, a);
                a = fmaf(p2, wa.z, a);
                a = fmaf(p3, wa.w, a);
                a = fmaf(p4, wb.x, a);
                a = fmaf(p5, wb.y, a);
                float h0 = gelu_f(a);
                const float4* w1r = (const float4*)(sw1 + i * 64 + H * 32);
#pragma unroll
                for (int k4 = 0; k4 < 8; ++k4) {
                    float4 wv = w1r[k4];
                    h1h[4 * k4 + 0] = fmaf(h0, wv.x, h1h[4 * k4 + 0]);
                    h1h[4 * k4 + 1] = fmaf(h0, wv.y, h1h[4 * k4 + 1]);
                    h1h[4 * k4 + 2] = fmaf(h0, wv.z, h1h[4 * k4 + 2]);
                    h1h[4 * k4 + 3] = fmaf(h0, wv.w, h1h[4 * k4 + 3]);
                }
            }
#pragma unroll
            for (int k = 0; k < 32; ++k) h1h[k] = gelu_f(h1h[k]);

            // layer-2 partial over this h1 half; merge via LDS atomics
#pragma unroll 1
            for (int jj = 0; jj < 16; ++jj) {
                float acc[8];
                if (H == 0) {
                    const float4* bb = (const float4*)(sb2 + jj * 8);
                    float4 c0 = bb[0], c1 = bb[1];
                    acc[0] = c0.x; acc[1] = c0.y; acc[2] = c0.z; acc[3] = c0.w;
                    acc[4] = c1.x; acc[5] = c1.y; acc[6] = c1.z; acc[7] = c1.w;
                } else {
#pragma unroll
                    for (int u = 0; u < 8; ++u) acc[u] = 0.f;
                }
                const float* w2c = sw2 + (H * 32) * 128 + jj * 8;
#pragma unroll
                for (int k = 0; k < 32; ++k) {
                    const float4* wr = (const float4*)(w2c + k * 128);
                    float4 w0v = wr[0], w1v = wr[1];
                    acc[0] = fmaf(h1h[k], w0v.x, acc[0]);
                    acc[1] = fmaf(h1h[k], w0v.y, acc[1]);
                    acc[2] = fmaf(h1h[k], w0v.z, acc[2]);
                    acc[3] = fmaf(h1h[k], w0v.w, acc[3]);
                    acc[4] = fmaf(h1h[k], w1v.x, acc[4]);
                    acc[5] = fmaf(h1h[k], w1v.y, acc[5]);
                    acc[6] = fmaf(h1h[k], w1v.z, acc[6]);
                    acc[7] = fmaf(h1h[k], w1v.w, acc[7]);
                }
                if (valid) {
                    float4 ra = r4[jj * 2], rb = r4[jj * 2 + 1];
                    atomicAdd(&aacc[jj * 8 + 0], acc[0] * ra.x);
                    atomicAdd(&aacc[jj * 8 + 1], acc[1] * ra.y);
                    atomicAdd(&aacc[jj * 8 + 2], acc[2] * ra.z);
                    atomicAdd(&aacc[jj * 8 + 3], acc[3] * ra.w);
                    atomicAdd(&aacc[jj * 8 + 4], acc[4] * rb.x);
                    atomicAdd(&aacc[jj * 8 + 5], acc[5] * rb.y);
                    atomicAdd(&aacc[jj * 8 + 6], acc[6] * rb.z);
                    atomicAdd(&aacc[jj * 8 + 7], acc[7] * rb.w);
                }
            }
        }
    }
    __syncthreads();

    if (!FUSED_PROJ) {
        // write per-query mean to global agg (coalesced across c)
        for (int idx = tid; idx < QB * 128; idx += BLOCK) {
            int ql = idx >> 7, c = idx & 127;
            int q  = q0 + ql;
            if (q < qend) {
                float deg = (float)(start[q + 1] - start[q]);
                agg[(size_t)q * 128 + c] = sacc[ql * 129 + c] / fmaxf(deg, 1.f);
            }
        }
    } else {
        if (tid < QB) {
            int q = q0 + tid;
            if (q < nq) {
                float deg = (float)(start[q + 1] - start[q]);
                float inv = 1.0f / fmaxf(deg, 1.f);
                const float* aq = &sacc[tid * 129];
                float o0 = pb1[0], o1 = pb1[1], o2 = pb1[2], o3 = pb1[3];
#pragma unroll 1
                for (int jj = 0; jj < 256; jj += 8) {
                    float acc[8];
#pragma unroll
                    for (int u = 0; u < 8; ++u) acc[u] = pb0[jj + u];
#pragma unroll
                    for (int i = 0; i < 128; ++i) {
                        float av = aq[i] * inv;
#pragma unroll
                        for (int u = 0; u < 8; ++u)
                            acc[u] = fmaf(av, P0[i * 256 + jj + u], acc[u]);
                    }
#pragma unroll
                    for (int u = 0; u < 8; ++u) {
                        float h = gelu_f(acc[u]);
                        o0 = fmaf(h, P1[(jj + u) * 4 + 0], o0);
                        o1 = fmaf(h, P1[(jj + u) * 4 + 1], o1);
                        o2 = fmaf(h, P1[(jj + u) * 4 + 2], o2);
                        o3 = fmaf(h, P1[(jj + u) * 4 + 3], o3);
                    }
                }
                float4* o4 = (float4*)(out + (size_t)q * 4);
                *o4 = make_float4(o0, o1, o2, o3);
            }
        }
    }
}

// ---------- projection (r7 proven; P0 via scalar path) ----------

__global__ __launch_bounds__(256) void proj_kernel(
    const float* __restrict__ agg,      // [NQ,128] mean
    const float* __restrict__ P0, const float* __restrict__ pb0,
    const float* __restrict__ P1, const float* __restrict__ pb1,
    float* __restrict__ out, int nq)
{
    int q = blockIdx.x * blockDim.x + threadIdx.x;
    if (q >= nq) return;

    float a[128];
    const float4* ag4 = (const float4*)(agg + (size_t)q * 128);
#pragma unroll
    for (int i = 0; i < 32; ++i) {
        float4 v = ag4[i];
        a[4 * i + 0] = v.x; a[4 * i + 1] = v.y;
        a[4 * i + 2] = v.z; a[4 * i + 3] = v.w;
    }

    float o0 = pb1[0], o1 = pb1[1], o2 = pb1[2], o3 = pb1[3];
#pragma unroll 1
    for (int jj = 0; jj < 256; jj += 8) {
        float acc[8];
#pragma unroll
        for (int u = 0; u < 8; ++u) acc[u] = pb0[jj + u];
#pragma unroll
        for (int i = 0; i < 128; ++i) {
            float av = a[i];
#pragma unroll
            for (int u = 0; u < 8; ++u)
                acc[u] = fmaf(av, P0[i * 256 + jj + u], acc[u]);
        }
#pragma unroll
        for (int u = 0; u < 8; ++u) {
            float h = gelu_f(acc[u]);
            o0 = fmaf(h, P1[(jj + u) * 4 + 0], o0);
            o1 = fmaf(h, P1[(jj + u) * 4 + 1], o1);
            o2 = fmaf(h, P1[(jj + u) * 4 + 2], o2);
            o3 = fmaf(h, P1[(jj + u) * 4 + 3], o3);
        }
    }
    float4* o4 = (float4*)(out + (size_t)q * 4);
    *o4 = make_float4(o0, o1, o2, o3);
}

extern "C" void kernel_launch(void* const* d_in, const int* in_sizes, int n_in,
                              void* d_out, int out_size, void* d_ws, size_t ws_size,
                              hipStream_t stream)
{
    const float* rndata = (const float*)d_in[0];
    const float* qpos   = (const float*)d_in[1];
    const float* lpos   = (const float*)d_in[2];
    const int*   dst    = (const int*)d_in[3];
    const int*   src    = (const int*)d_in[4];
    const float* W0  = (const float*)d_in[5];
    const float* b0  = (const float*)d_in[6];
    const float* W1  = (const float*)d_in[7];
    const float* b1  = (const float*)d_in[8];
    const float* W2  = (const float*)d_in[9];
    const float* b2  = (const float*)d_in[10];
    const float* P0  = (const float*)d_in[11];
    const float* pb0 = (const float*)d_in[12];
    const float* P1  = (const float*)d_in[13];
    const float* pb1 = (const float*)d_in[14];

    int nq = in_sizes[1] / 3;
    int E  = in_sizes[3];

    // ws layout: [agg nq*128 (path A)] [hist] [cursor] [start] [dsts] [srcs]
    size_t agg_bytes  = (size_t)nq * 128 * sizeof(float);
    size_t sort_bytes = 0;
    {
        size_t o = 0;
        o += ((size_t)nq * sizeof(int) + 15) & ~(size_t)15;
        o += ((size_t)nq * sizeof(int) + 15) & ~(size_t)15;
        o += ((size_t)(nq + 1) * sizeof(int) + 15) & ~(size_t)15;
        o += ((size_t)E * sizeof(int) + 15) & ~(size_t)15;
        o += ((size_t)E * sizeof(int) + 15) & ~(size_t)15;
        sort_bytes = o;
    }
    bool path_a = (agg_bytes + sort_bytes) <= ws_size;

    size_t off = path_a ? agg_bytes : 0;
    auto alloc = [&](size_t bytes) {
        void* p = (char*)d_ws + off;
        off += (bytes + 15) & ~(size_t)15;
        return p;
    };
    float* agg   = (float*)d_ws;  // path A only
    int* hist    = (int*)alloc((size_t)nq * sizeof(int));
    int* cursor  = (int*)alloc((size_t)nq * sizeof(int));
    int* start   = (int*)alloc((size_t)(nq + 1) * sizeof(int));
    int* dsts    = (int*)alloc((size_t)E * sizeof(int));
    int* srcs    = (int*)alloc((size_t)E * sizeof(int));

    size_t histpad = ((size_t)nq * sizeof(int) + 15) & ~(size_t)15;
    hipMemsetAsync(hist, 0, 2 * histpad, stream);

    hist_kernel<<<(E + 255) / 256, 256, 0, stream>>>(dst, hist, E);
    scan_kernel<<<1, 1024, 0, stream>>>(hist, start, nq);
    scatter_kernel<<<(E + 255) / 256, 256, 0, stream>>>(dst, src, start, cursor, dsts, srcs, E);

    constexpr int    QB_BIG     = 196;
    constexpr int    QB_SMALL   = 23;
    constexpr size_t SMEM_BIG   = (size_t)(12992 + QB_BIG   * 129) * 4;  // 153,104 B
    constexpr size_t SMEM_SMALL = (size_t)(12992 + QB_SMALL * 129) * 4;  // 63,836 B

    if (path_a) {
        bool big = hipFuncSetAttribute(
            reinterpret_cast<const void*>(&fused_kernel<QB_BIG, false>),
            hipFuncAttributeMaxDynamicSharedMemorySize, (int)SMEM_BIG) == hipSuccess;
        if (big) {
            int nb = (nq + QB_BIG - 1) / QB_BIG;
            fused_kernel<QB_BIG, false><<<nb, BLOCK, SMEM_BIG, stream>>>(
                rndata, qpos, lpos, dsts, srcs, start,
                W0, b0, W1, b1, W2, b2, P0, pb0, P1, pb1, agg, nullptr, nq);
        } else {
            int nb = (nq + QB_SMALL - 1) / QB_SMALL;
            fused_kernel<QB_SMALL, false><<<nb, BLOCK, SMEM_SMALL, stream>>>(
                rndata, qpos, lpos, dsts, srcs, start,
                W0, b0, W1, b1, W2, b2, P0, pb0, P1, pb1, agg, nullptr, nq);
        }
        proj_kernel<<<(nq + 255) / 256, 256, 0, stream>>>(
            agg, P0, pb0, P1, pb1, (float*)d_out, nq);
    } else {
        bool big = hipFuncSetAttribute(
            reinterpret_cast<const void*>(&fused_kernel<QB_BIG, true>),
            hipFuncAttributeMaxDynamicSharedMemorySize, (int)SMEM_BIG) == hipSuccess;
        if (big) {
            int nb = (nq + QB_BIG - 1) / QB_BIG;
            fused_kernel<QB_BIG, true><<<nb, BLOCK, SMEM_BIG, stream>>>(
                rndata, qpos, lpos, dsts, srcs, start,
                W0, b0, W1, b1, W2, b2, P0, pb0, P1, pb1, nullptr, (float*)d_out, nq);
        } else {
            int nb = (nq + QB_SMALL - 1) / QB_SMALL;
            fused_kernel<QB_SMALL, true><<<nb, BLOCK, SMEM_SMALL, stream>>>(
                rndata, qpos, lpos, dsts, srcs, start,
                W0, b0, W1, b1, W2, b2, P0, pb0, P1, pb1, nullptr, (float*)d_out, nq);
        }
    }
}

// Round 10
// 2360.302 us; speedup vs baseline: 1.1371x; 1.1155x over previous
//
#include <hip/hip_runtime.h>

// GNODecoder round 10: r4/r7/r9 are LDS-ISSUE-bound: lane-per-edge bodies
// read every weight per edge at a 1:4 read:FMA ratio, and the allocator's
// hard VGPR caps (64@1024thr, 128@256thr) forbid the 2-edge fix. New
// structure: block-cooperative register-tiled GEMM. 512-thr block owns QB=48
// queries; edge range processed in 128-edge tiles: gather einT -> L0/L1/L2
// GEMMs with LDS-transposed activations (h0T/h1T[64][132]) and 4m x 4n
// C-tiles in registers (C16+A4+B4 ~ 40 regs, fits 64-VGPR grant). Per k:
// 2 ds_read_b128 feed 16 FMAs (1:8) with 16 independent FMAs per read.
// Epilogue: C * rndata[src] (global, L3-cached) -> ds_add sacc.
// LDS 147.2 KB -> 1 block/CU, 8 waves. proj: P0 column-chunked LDS staging.

#define BLOCK 512

// LDS float offsets
#define OFF_W0   0      // [6][64]
#define OFF_B0   384    // [64]
#define OFF_W1   448    // [64][64]
#define OFF_B1   4544   // [64]
#define OFF_W2   4608   // [64][128]
#define OFF_B2   12800  // [128]
#define OFF_EIN  12928  // [6][132]
#define OFF_H0   13720  // [64][132]
#define OFF_H1   22168  // [64][132]
#define OFF_SACC 30616  // [QB*129]

#define FMA4(C, A, s) \
    C.x = fmaf(A.x, s, C.x); C.y = fmaf(A.y, s, C.y); \
    C.z = fmaf(A.z, s, C.z); C.w = fmaf(A.w, s, C.w)

__device__ __forceinline__ float gelu_f(float x) {
    // jax.nn.gelu default (approximate=True, tanh form)
    float x3 = x * x * x;
    float t  = 0.7978845608028654f * fmaf(0.044715f, x3, x);
    float e  = __expf(2.0f * t);
    float r  = __builtin_amdgcn_rcpf(e + 1.0f);
    return 0.5f * x * (1.0f + (1.0f - 2.0f * r));
}

__device__ __forceinline__ float4 gelu4(float4 v) {
    return make_float4(gelu_f(v.x), gelu_f(v.y), gelu_f(v.z), gelu_f(v.w));
}

// ---------- sort machinery (proven) ----------

__global__ void hist_kernel(const int* __restrict__ dst, int* __restrict__ hist, int E) {
    int e = blockIdx.x * blockDim.x + threadIdx.x;
    if (e < E) atomicAdd(&hist[dst[e]], 1);
}

__global__ __launch_bounds__(1024) void scan_kernel(const int* __restrict__ hist,
                                                    int* __restrict__ start, int n) {
    __shared__ int wsum[16];
    __shared__ int woff[16];
    int tid = threadIdx.x;
    int lane = tid & 63, wid = tid >> 6;
    int carry = 0;  // meaningful on tid 0 only
    for (int base = 0; base < n; base += 1024) {
        int i = base + tid;
        int v = (i < n) ? hist[i] : 0;
        int incl = v;
#pragma unroll
        for (int off = 1; off < 64; off <<= 1) {
            int t = __shfl_up(incl, off, 64);
            if (lane >= off) incl += t;
        }
        if (lane == 63) wsum[wid] = incl;
        __syncthreads();
        if (tid == 0) {
            int acc = carry;
#pragma unroll
            for (int w = 0; w < 16; ++w) { woff[w] = acc; acc += wsum[w]; }
            carry = acc;
        }
        __syncthreads();
        if (i < n) start[i] = woff[wid] + incl - v;
        __syncthreads();
    }
    if (threadIdx.x == 0) start[n] = carry;
}

__global__ void scatter_kernel(const int* __restrict__ dst, const int* __restrict__ src,
                               const int* __restrict__ start, int* __restrict__ cursor,
                               int* __restrict__ dsts, int* __restrict__ srcs, int E) {
    int e = blockIdx.x * blockDim.x + threadIdx.x;
    if (e >= E) return;
    int d = dst[e];
    int pos = start[d] + atomicAdd(&cursor[d], 1);
    dsts[pos] = d;
    srcs[pos] = src[e];
}

// ---------- fused: block-cooperative tiled GEMM over sorted edges ----------

template <int QB, bool FUSED_PROJ>
__global__ __launch_bounds__(BLOCK) void fused_kernel(
    const float* __restrict__ rndata,   // [NL,128]
    const float* __restrict__ qpos,     // [NQ,3]
    const float* __restrict__ lpos,     // [NL,3]
    const int*   __restrict__ dsts,     // [E] sorted by dst
    const int*   __restrict__ srcs,     // [E]
    const int*   __restrict__ start,    // [NQ+1]
    const float* __restrict__ W0, const float* __restrict__ b0,
    const float* __restrict__ W1, const float* __restrict__ b1,
    const float* __restrict__ W2, const float* __restrict__ b2,
    const float* __restrict__ P0, const float* __restrict__ pb0,
    const float* __restrict__ P1, const float* __restrict__ pb1,
    float* __restrict__ agg,            // [NQ,128] mean (path A)
    float* __restrict__ out,            // [NQ,4]   (FUSED_PROJ)
    int nq)
{
    extern __shared__ float smem[];
    const int tid = threadIdx.x;

    // ---- stage weights ----
    {
        float4* s4 = (float4*)(smem + OFF_W1);
        const float4* g4 = (const float4*)W1;
        for (int i = tid; i < 1024; i += BLOCK) s4[i] = g4[i];
        s4 = (float4*)(smem + OFF_W2); g4 = (const float4*)W2;
        for (int i = tid; i < 2048; i += BLOCK) s4[i] = g4[i];
        if (tid < 96)       ((float4*)(smem + OFF_W0))[tid]       = ((const float4*)W0)[tid];
        else if (tid < 112) ((float4*)(smem + OFF_B0))[tid - 96]  = ((const float4*)b0)[tid - 96];
        else if (tid < 128) ((float4*)(smem + OFF_B1))[tid - 112] = ((const float4*)b1)[tid - 112];
        else if (tid < 160) ((float4*)(smem + OFF_B2))[tid - 128] = ((const float4*)b2)[tid - 128];
    }
    for (int i = tid; i < QB * 129; i += BLOCK) smem[OFF_SACC + i] = 0.f;

    float* einT = smem + OFF_EIN;   // [6][132]
    float* h0T  = smem + OFF_H0;    // [64][132]
    float* h1T  = smem + OFF_H1;    // [64][132]
    float* sacc = smem + OFF_SACC;  // [QB][129]

    const int q0   = blockIdx.x * QB;
    const int qend = min(q0 + QB, nq);
    const int e0 = start[q0], e1 = start[qend];
    const int ntiles = (e1 - e0 + 127) >> 7;

    const int w = tid >> 6, lane = tid & 63;
    const int mg = lane & 15, ng = lane >> 4;
    const int m0  = (w & 1) * 64;
    const int n0q = (w >> 1) * 16;      // L0/L1 n-base (covers N=64)
    const int nb2 = (w >> 1) * 32;      // L2 n-base (covers N=128, 2 passes)
    const int mm = m0 + mg * 4;

    for (int t = 0; t < ntiles; ++t) {
        const int ebase = e0 + (t << 7);

        // ---- gather einT (threads 0..127, one edge each) ----
        if (tid < 128) {
            int e = ebase + tid;
            if (e < e1) {
                int d = dsts[e], s = srcs[e];
                einT[0 * 132 + tid] = qpos[d * 3 + 0];
                einT[1 * 132 + tid] = qpos[d * 3 + 1];
                einT[2 * 132 + tid] = qpos[d * 3 + 2];
                einT[3 * 132 + tid] = lpos[s * 3 + 0];
                einT[4 * 132 + tid] = lpos[s * 3 + 1];
                einT[5 * 132 + tid] = lpos[s * 3 + 2];
            } else {
#pragma unroll
                for (int c = 0; c < 6; ++c) einT[c * 132 + tid] = 0.f;
            }
        }
        __syncthreads();

        // ---- L0: [128,6] x [6,64] -> h0T ----
        {
            const int nn = n0q + ng * 4;
            float4 bb = *(const float4*)(smem + OFF_B0 + nn);
            float4 c0 = make_float4(bb.x, bb.x, bb.x, bb.x);
            float4 c1 = make_float4(bb.y, bb.y, bb.y, bb.y);
            float4 c2 = make_float4(bb.z, bb.z, bb.z, bb.z);
            float4 c3 = make_float4(bb.w, bb.w, bb.w, bb.w);
#pragma unroll
            for (int k = 0; k < 6; ++k) {
                float4 A = *(const float4*)(einT + k * 132 + mm);
                float4 B = *(const float4*)(smem + OFF_W0 + k * 64 + nn);
                FMA4(c0, A, B.x); FMA4(c1, A, B.y);
                FMA4(c2, A, B.z); FMA4(c3, A, B.w);
            }
            c0 = gelu4(c0); c1 = gelu4(c1); c2 = gelu4(c2); c3 = gelu4(c3);
            *(float4*)(h0T + (nn + 0) * 132 + mm) = c0;
            *(float4*)(h0T + (nn + 1) * 132 + mm) = c1;
            *(float4*)(h0T + (nn + 2) * 132 + mm) = c2;
            *(float4*)(h0T + (nn + 3) * 132 + mm) = c3;
        }
        __syncthreads();

        // ---- L1: [128,64] x [64,64] -> h1T ----
        {
            const int nn = n0q + ng * 4;
            float4 bb = *(const float4*)(smem + OFF_B1 + nn);
            float4 c0 = make_float4(bb.x, bb.x, bb.x, bb.x);
            float4 c1 = make_float4(bb.y, bb.y, bb.y, bb.y);
            float4 c2 = make_float4(bb.z, bb.z, bb.z, bb.z);
            float4 c3 = make_float4(bb.w, bb.w, bb.w, bb.w);
#pragma unroll 2
            for (int k = 0; k < 64; ++k) {
                float4 A = *(const float4*)(h0T + k * 132 + mm);
                float4 B = *(const float4*)(smem + OFF_W1 + k * 64 + nn);
                FMA4(c0, A, B.x); FMA4(c1, A, B.y);
                FMA4(c2, A, B.z); FMA4(c3, A, B.w);
            }
            c0 = gelu4(c0); c1 = gelu4(c1); c2 = gelu4(c2); c3 = gelu4(c3);
            *(float4*)(h1T + (nn + 0) * 132 + mm) = c0;
            *(float4*)(h1T + (nn + 1) * 132 + mm) = c1;
            *(float4*)(h1T + (nn + 2) * 132 + mm) = c2;
            *(float4*)(h1T + (nn + 3) * 132 + mm) = c3;
        }
        __syncthreads();

        // ---- L2: [128,64] x [64,128], * rndata[src], ds_add into sacc ----
        {
            // edge meta for this lane's 4 m-rows
            int ed[4], es[4];
#pragma unroll
            for (int m = 0; m < 4; ++m) {
                int e = ebase + mm + m;
                bool v = e < e1;
                ed[m] = v ? dsts[e] : -1;
                es[m] = v ? srcs[e] : 0;
            }
#pragma unroll 1
            for (int p = 0; p < 2; ++p) {
                const int nn = nb2 + p * 16 + ng * 4;
                float4 bb = *(const float4*)(smem + OFF_B2 + nn);
                float4 c0 = make_float4(bb.x, bb.x, bb.x, bb.x);
                float4 c1 = make_float4(bb.y, bb.y, bb.y, bb.y);
                float4 c2 = make_float4(bb.z, bb.z, bb.z, bb.z);
                float4 c3 = make_float4(bb.w, bb.w, bb.w, bb.w);
#pragma unroll 2
                for (int k = 0; k < 64; ++k) {
                    float4 A = *(const float4*)(h1T + k * 132 + mm);
                    float4 B = *(const float4*)(smem + OFF_W2 + k * 128 + nn);
                    FMA4(c0, A, B.x); FMA4(c1, A, B.y);
                    FMA4(c2, A, B.z); FMA4(c3, A, B.w);
                }
                // epilogue: per m-row multiply by rndata[src] and scatter-add
#define L2_EPI(mi, comp)                                                     \
                if (ed[mi] >= 0) {                                           \
                    float4 r = *(const float4*)(rndata + (size_t)es[mi] * 128 + nn); \
                    float* ac = &sacc[(ed[mi] - q0) * 129 + nn];             \
                    atomicAdd(&ac[0], c0.comp * r.x);                        \
                    atomicAdd(&ac[1], c1.comp * r.y);                        \
                    atomicAdd(&ac[2], c2.comp * r.z);                        \
                    atomicAdd(&ac[3], c3.comp * r.w);                        \
                }
                L2_EPI(0, x)
                L2_EPI(1, y)
                L2_EPI(2, z)
                L2_EPI(3, w)
#undef L2_EPI
            }
        }
        __syncthreads();
    }

    if (!FUSED_PROJ) {
        // write per-query mean to global agg (coalesced across c)
        for (int idx = tid; idx < QB * 128; idx += BLOCK) {
            int ql = idx >> 7, c = idx & 127;
            int q  = q0 + ql;
            if (q < qend) {
                float deg = (float)(start[q + 1] - start[q]);
                agg[(size_t)q * 128 + c] = sacc[ql * 129 + c] / fmaxf(deg, 1.f);
            }
        }
    } else {
        if (tid < QB) {
            int q = q0 + tid;
            if (q < nq) {
                float deg = (float)(start[q + 1] - start[q]);
                float inv = 1.0f / fmaxf(deg, 1.f);
                const float* aq = &sacc[tid * 129];
                float o0 = pb1[0], o1 = pb1[1], o2 = pb1[2], o3 = pb1[3];
#pragma unroll 1
                for (int jj = 0; jj < 256; jj += 8) {
                    float acc[8];
#pragma unroll
                    for (int u = 0; u < 8; ++u) acc[u] = pb0[jj + u];
#pragma unroll
                    for (int i = 0; i < 128; ++i) {
                        float av = aq[i] * inv;
#pragma unroll
                        for (int u = 0; u < 8; ++u)
                            acc[u] = fmaf(av, P0[i * 256 + jj + u], acc[u]);
                    }
#pragma unroll
                    for (int u = 0; u < 8; ++u) {
                        float h = gelu_f(acc[u]);
                        o0 = fmaf(h, P1[(jj + u) * 4 + 0], o0);
                        o1 = fmaf(h, P1[(jj + u) * 4 + 1], o1);
                        o2 = fmaf(h, P1[(jj + u) * 4 + 2], o2);
                        o3 = fmaf(h, P1[(jj + u) * 4 + 3], o3);
                    }
                }
                float4* o4 = (float4*)(out + (size_t)q * 4);
                *o4 = make_float4(o0, o1, o2, o3);
            }
        }
    }
}

// ---------- projection: P0 column-chunked through LDS ----------
// static shared: P0c[128][64] | P1[256*4] | pb0[256] | pb1[4]  = 37.9 KB

__global__ __launch_bounds__(256) void proj_kernel(
    const float* __restrict__ agg,      // [NQ,128] mean
    const float* __restrict__ P0, const float* __restrict__ pb0,
    const float* __restrict__ P1, const float* __restrict__ pb1,
    float* __restrict__ out, int nq)
{
    __shared__ float sm[8192 + 1024 + 256 + 4];
    float* sP0c = sm;             // [128][64]
    float* sP1  = sm + 8192;      // [256][4]
    float* spb0 = sm + 9216;      // [256]
    float* spb1 = sm + 9472;      // [4]

    const int tid = threadIdx.x;
    {
        float4* s4 = (float4*)sP1;
        const float4* g4 = (const float4*)P1;
        if (tid < 256) s4[tid] = g4[tid];
        if (tid < 64) ((float4*)spb0)[tid] = ((const float4*)pb0)[tid];
        if (tid == 0) ((float4*)spb1)[0] = ((const float4*)pb1)[0];
    }

    const int q = blockIdx.x * blockDim.x + tid;
    float a[128];
    if (q < nq) {
        const float4* ag4 = (const float4*)(agg + (size_t)q * 128);
#pragma unroll
        for (int i = 0; i < 32; ++i) {
            float4 v = ag4[i];
            a[4 * i + 0] = v.x; a[4 * i + 1] = v.y;
            a[4 * i + 2] = v.z; a[4 * i + 3] = v.w;
        }
    }

    float o0 = 0.f, o1 = 0.f, o2 = 0.f, o3 = 0.f;

#pragma unroll 1
    for (int c = 0; c < 4; ++c) {
        __syncthreads();  // previous chunk's compute done
        {
            float4* s4 = (float4*)sP0c;
            const float4* g4 = (const float4*)P0;  // [128][64 f4]
            for (int idx = tid; idx < 2048; idx += 256) {
                int row = idx >> 4, col4 = idx & 15;
                s4[idx] = g4[row * 64 + c * 16 + col4];
            }
        }
        __syncthreads();
        if (q < nq) {
            if (c == 0) { o0 = spb1[0]; o1 = spb1[1]; o2 = spb1[2]; o3 = spb1[3]; }
#pragma unroll 1
            for (int jjb = 0; jjb < 8; ++jjb) {
                int jl = jjb * 8;
                float acc[8];
#pragma unroll
                for (int u = 0; u < 8; ++u) acc[u] = spb0[c * 64 + jl + u];
#pragma unroll 2
                for (int i = 0; i < 128; ++i) {
                    float av = a[i];
                    float4 w0v = *(const float4*)(sP0c + i * 64 + jl);
                    float4 w1v = *(const float4*)(sP0c + i * 64 + jl + 4);
                    acc[0] = fmaf(av, w0v.x, acc[0]);
                    acc[1] = fmaf(av, w0v.y, acc[1]);
                    acc[2] = fmaf(av, w0v.z, acc[2]);
                    acc[3] = fmaf(av, w0v.w, acc[3]);
                    acc[4] = fmaf(av, w1v.x, acc[4]);
                    acc[5] = fmaf(av, w1v.y, acc[5]);
                    acc[6] = fmaf(av, w1v.z, acc[6]);
                    acc[7] = fmaf(av, w1v.w, acc[7]);
                }
#pragma unroll
                for (int u = 0; u < 8; ++u) {
                    float h = gelu_f(acc[u]);
                    const float* p1r = sP1 + (c * 64 + jl + u) * 4;
                    o0 = fmaf(h, p1r[0], o0);
                    o1 = fmaf(h, p1r[1], o1);
                    o2 = fmaf(h, p1r[2], o2);
                    o3 = fmaf(h, p1r[3], o3);
                }
            }
        }
    }
    if (q < nq) {
        float4* o4 = (float4*)(out + (size_t)q * 4);
        *o4 = make_float4(o0, o1, o2, o3);
    }
}

extern "C" void kernel_launch(void* const* d_in, const int* in_sizes, int n_in,
                              void* d_out, int out_size, void* d_ws, size_t ws_size,
                              hipStream_t stream)
{
    const float* rndata = (const float*)d_in[0];
    const float* qpos   = (const float*)d_in[1];
    const float* lpos   = (const float*)d_in[2];
    const int*   dst    = (const int*)d_in[3];
    const int*   src    = (const int*)d_in[4];
    const float* W0  = (const float*)d_in[5];
    const float* b0  = (const float*)d_in[6];
    const float* W1  = (const float*)d_in[7];
    const float* b1  = (const float*)d_in[8];
    const float* W2  = (const float*)d_in[9];
    const float* b2  = (const float*)d_in[10];
    const float* P0  = (const float*)d_in[11];
    const float* pb0 = (const float*)d_in[12];
    const float* P1  = (const float*)d_in[13];
    const float* pb1 = (const float*)d_in[14];

    int nq = in_sizes[1] / 3;
    int E  = in_sizes[3];

    // ws layout: [agg nq*128 (path A)] [hist] [cursor] [start] [dsts] [srcs]
    size_t agg_bytes  = (size_t)nq * 128 * sizeof(float);
    size_t sort_bytes = 0;
    {
        size_t o = 0;
        o += ((size_t)nq * sizeof(int) + 15) & ~(size_t)15;
        o += ((size_t)nq * sizeof(int) + 15) & ~(size_t)15;
        o += ((size_t)(nq + 1) * sizeof(int) + 15) & ~(size_t)15;
        o += ((size_t)E * sizeof(int) + 15) & ~(size_t)15;
        o += ((size_t)E * sizeof(int) + 15) & ~(size_t)15;
        sort_bytes = o;
    }
    bool path_a = (agg_bytes + sort_bytes) <= ws_size;

    size_t off = path_a ? agg_bytes : 0;
    auto alloc = [&](size_t bytes) {
        void* p = (char*)d_ws + off;
        off += (bytes + 15) & ~(size_t)15;
        return p;
    };
    float* agg   = (float*)d_ws;  // path A only
    int* hist    = (int*)alloc((size_t)nq * sizeof(int));
    int* cursor  = (int*)alloc((size_t)nq * sizeof(int));
    int* start   = (int*)alloc((size_t)(nq + 1) * sizeof(int));
    int* dsts    = (int*)alloc((size_t)E * sizeof(int));
    int* srcs    = (int*)alloc((size_t)E * sizeof(int));

    size_t histpad = ((size_t)nq * sizeof(int) + 15) & ~(size_t)15;
    hipMemsetAsync(hist, 0, 2 * histpad, stream);

    hist_kernel<<<(E + 255) / 256, 256, 0, stream>>>(dst, hist, E);
    scan_kernel<<<1, 1024, 0, stream>>>(hist, start, nq);
    scatter_kernel<<<(E + 255) / 256, 256, 0, stream>>>(dst, src, start, cursor, dsts, srcs, E);

    constexpr int    QB = 48;
    constexpr size_t SMEM = (size_t)(30616 + QB * 129) * 4;  // 147,232 B
    int nb = (nq + QB - 1) / QB;

    if (path_a) {
        (void)hipFuncSetAttribute(
            reinterpret_cast<const void*>(&fused_kernel<QB, false>),
            hipFuncAttributeMaxDynamicSharedMemorySize, (int)SMEM);
        fused_kernel<QB, false><<<nb, BLOCK, SMEM, stream>>>(
            rndata, qpos, lpos, dsts, srcs, start,
            W0, b0, W1, b1, W2, b2, P0, pb0, P1, pb1, agg, nullptr, nq);
        proj_kernel<<<(nq + 255) / 256, 256, 0, stream>>>(
            agg, P0, pb0, P1, pb1, (float*)d_out, nq);
    } else {
        (void)hipFuncSetAttribute(
            reinterpret_cast<const void*>(&fused_kernel<QB, true>),
            hipFuncAttributeMaxDynamicSharedMemorySize, (int)SMEM);
        fused_kernel<QB, true><<<nb, BLOCK, SMEM, stream>>>(
            rndata, qpos, lpos, dsts, srcs, start,
            W0, b0, W1, b1, W2, b2, P0, pb0, P1, pb1, nullptr, (float*)d_out, nq);
    }
}

// Round 11
// 2209.164 us; speedup vs baseline: 1.2149x; 1.0684x over previous
//
#include <hip/hip_runtime.h>

// GNODecoder round 11: r10's tiled GEMM was latency-bound (VALUBusy 20.7%,
// 1 block/CU = 2 waves/SIMD, LDS pipe also carrying all weight reads).
// Changes: (1) B (W1/W2) read from GLOBAL (L1/L2-cached) in the k-loops --
// vector pipe, LDS pipe serves only A; (2) single hT buffer: L1 keeps its
// C-tile in regs across a barrier then overwrites h0 with h1 (-33.8 KB);
// (3) LDS 51.9 KB (QB=24) -> 3 blocks/CU = 24 waves (3x residency);
// (4) L2 tile Cm=4 x Cn=8: 1 LDS read : 32 FMAs per k -> VALU-bound balance.

#define BLOCK 512

// LDS float offsets
#define OFF_W0   0      // [6][64] = 384
#define OFF_B0   384    // [64]
#define OFF_B1   448    // [64]
#define OFF_B2   512    // [128]
#define OFF_EIN  640    // [6][132] = 792
#define OFF_HT   1432   // [64][132] = 8448 (h0 then h1)
#define OFF_SACC 9880   // [QB*129]

__device__ __forceinline__ float gelu_f(float x) {
    // jax.nn.gelu default (approximate=True, tanh form)
    float x3 = x * x * x;
    float t  = 0.7978845608028654f * fmaf(0.044715f, x3, x);
    float e  = __expf(2.0f * t);
    float r  = __builtin_amdgcn_rcpf(e + 1.0f);
    return 0.5f * x * (1.0f + (1.0f - 2.0f * r));
}

// ---------- sort machinery (proven) ----------

__global__ void hist_kernel(const int* __restrict__ dst, int* __restrict__ hist, int E) {
    int e = blockIdx.x * blockDim.x + threadIdx.x;
    if (e < E) atomicAdd(&hist[dst[e]], 1);
}

__global__ __launch_bounds__(1024) void scan_kernel(const int* __restrict__ hist,
                                                    int* __restrict__ start, int n) {
    __shared__ int wsum[16];
    __shared__ int woff[16];
    int tid = threadIdx.x;
    int lane = tid & 63, wid = tid >> 6;
    int carry = 0;  // meaningful on tid 0 only
    for (int base = 0; base < n; base += 1024) {
        int i = base + tid;
        int v = (i < n) ? hist[i] : 0;
        int incl = v;
#pragma unroll
        for (int off = 1; off < 64; off <<= 1) {
            int t = __shfl_up(incl, off, 64);
            if (lane >= off) incl += t;
        }
        if (lane == 63) wsum[wid] = incl;
        __syncthreads();
        if (tid == 0) {
            int acc = carry;
#pragma unroll
            for (int w = 0; w < 16; ++w) { woff[w] = acc; acc += wsum[w]; }
            carry = acc;
        }
        __syncthreads();
        if (i < n) start[i] = woff[wid] + incl - v;
        __syncthreads();
    }
    if (threadIdx.x == 0) start[n] = carry;
}

__global__ void scatter_kernel(const int* __restrict__ dst, const int* __restrict__ src,
                               const int* __restrict__ start, int* __restrict__ cursor,
                               int* __restrict__ dsts, int* __restrict__ srcs, int E) {
    int e = blockIdx.x * blockDim.x + threadIdx.x;
    if (e >= E) return;
    int d = dst[e];
    int pos = start[d] + atomicAdd(&cursor[d], 1);
    dsts[pos] = d;
    srcs[pos] = src[e];
}

// ---------- fused: tiled GEMM, weights-from-global, single hT buffer ----------

template <int QB, bool FUSED_PROJ>
__global__ __launch_bounds__(BLOCK) void fused_kernel(
    const float* __restrict__ rndata,   // [NL,128]
    const float* __restrict__ qpos,     // [NQ,3]
    const float* __restrict__ lpos,     // [NL,3]
    const int*   __restrict__ dsts,     // [E] sorted by dst
    const int*   __restrict__ srcs,     // [E]
    const int*   __restrict__ start,    // [NQ+1]
    const float* __restrict__ W0, const float* __restrict__ b0,
    const float* __restrict__ W1, const float* __restrict__ b1,
    const float* __restrict__ W2, const float* __restrict__ b2,
    const float* __restrict__ P0, const float* __restrict__ pb0,
    const float* __restrict__ P1, const float* __restrict__ pb1,
    float* __restrict__ agg,            // [NQ,128] mean (path A)
    float* __restrict__ out,            // [NQ,4]   (FUSED_PROJ)
    int nq)
{
    extern __shared__ float smem[];
    const int tid = threadIdx.x;

    // ---- stage small weights (W0 + biases); W1/W2 stay in global/L1 ----
    if (tid < 96)       ((float4*)(smem + OFF_W0))[tid]       = ((const float4*)W0)[tid];
    else if (tid < 112) ((float4*)(smem + OFF_B0))[tid - 96]  = ((const float4*)b0)[tid - 96];
    else if (tid < 128) ((float4*)(smem + OFF_B1))[tid - 112] = ((const float4*)b1)[tid - 112];
    else if (tid < 160) ((float4*)(smem + OFF_B2))[tid - 128] = ((const float4*)b2)[tid - 128];
    for (int i = tid; i < QB * 129; i += BLOCK) smem[OFF_SACC + i] = 0.f;

    float* einT = smem + OFF_EIN;   // [6][132]
    float* hT   = smem + OFF_HT;    // [64][132]
    float* sacc = smem + OFF_SACC;  // [QB][129]

    const int q0   = blockIdx.x * QB;
    const int qend = min(q0 + QB, nq);
    const int e0 = start[q0], e1 = start[qend];
    const int ntiles = (e1 - e0 + 127) >> 7;

    const int w = tid >> 6, lane = tid & 63;
    const int mg = lane & 15, ng = lane >> 4;
    const int mm  = (w & 1) * 64 + mg * 4;   // 4 m-rows (edges) per lane
    const int nc1 = (w >> 1) * 16 + ng * 4;  // L0/L1 n-base (N=64)
    const int nc2 = (w >> 1) * 32 + ng * 8;  // L2 n-base (N=128)

    for (int t = 0; t < ntiles; ++t) {
        const int ebase = e0 + (t << 7);

        // ---- gather einT (threads 0..127) ----
        if (tid < 128) {
            int e = ebase + tid;
            if (e < e1) {
                int d = dsts[e], s = srcs[e];
                einT[0 * 132 + tid] = qpos[d * 3 + 0];
                einT[1 * 132 + tid] = qpos[d * 3 + 1];
                einT[2 * 132 + tid] = qpos[d * 3 + 2];
                einT[3 * 132 + tid] = lpos[s * 3 + 0];
                einT[4 * 132 + tid] = lpos[s * 3 + 1];
                einT[5 * 132 + tid] = lpos[s * 3 + 2];
            } else {
#pragma unroll
                for (int c = 0; c < 6; ++c) einT[c * 132 + tid] = 0.f;
            }
        }
        __syncthreads();  // einT ready (first iter: staging too)

        // ---- L0: [128,6] x [6,64] -> hT (h0), B from LDS ----
        {
            float C[4][4];
            float4 bb = *(const float4*)(smem + OFF_B0 + nc1);
            float bv[4] = {bb.x, bb.y, bb.z, bb.w};
#pragma unroll
            for (int j = 0; j < 4; ++j)
#pragma unroll
                for (int m = 0; m < 4; ++m) C[j][m] = bv[j];
#pragma unroll
            for (int k = 0; k < 6; ++k) {
                float4 a = *(const float4*)(einT + k * 132 + mm);
                float av[4] = {a.x, a.y, a.z, a.w};
                float4 B = *(const float4*)(smem + OFF_W0 + k * 64 + nc1);
                float bs[4] = {B.x, B.y, B.z, B.w};
#pragma unroll
                for (int j = 0; j < 4; ++j)
#pragma unroll
                    for (int m = 0; m < 4; ++m)
                        C[j][m] = fmaf(av[m], bs[j], C[j][m]);
            }
#pragma unroll
            for (int j = 0; j < 4; ++j) {
                float4 o = make_float4(gelu_f(C[j][0]), gelu_f(C[j][1]),
                                       gelu_f(C[j][2]), gelu_f(C[j][3]));
                *(float4*)(hT + (nc1 + j) * 132 + mm) = o;
            }
        }
        __syncthreads();  // h0 ready

        // ---- L1: [128,64] x [64,64], B=W1 from GLOBAL; C in regs ----
        float C1[4][4];
        {
            float4 bb = *(const float4*)(smem + OFF_B1 + nc1);
            float bv[4] = {bb.x, bb.y, bb.z, bb.w};
#pragma unroll
            for (int j = 0; j < 4; ++j)
#pragma unroll
                for (int m = 0; m < 4; ++m) C1[j][m] = bv[j];
#pragma unroll 4
            for (int k = 0; k < 64; ++k) {
                float4 a = *(const float4*)(hT + k * 132 + mm);
                float av[4] = {a.x, a.y, a.z, a.w};
                float4 B = *(const float4*)(W1 + k * 64 + nc1);
                float bs[4] = {B.x, B.y, B.z, B.w};
#pragma unroll
                for (int j = 0; j < 4; ++j)
#pragma unroll
                    for (int m = 0; m < 4; ++m)
                        C1[j][m] = fmaf(av[m], bs[j], C1[j][m]);
            }
        }
        __syncthreads();  // all waves done READING h0

        // write h1 = gelu(C1) over hT
#pragma unroll
        for (int j = 0; j < 4; ++j) {
            float4 o = make_float4(gelu_f(C1[j][0]), gelu_f(C1[j][1]),
                                   gelu_f(C1[j][2]), gelu_f(C1[j][3]));
            *(float4*)(hT + (nc1 + j) * 132 + mm) = o;
        }
        __syncthreads();  // h1 ready

        // ---- L2: [128,64] x [64,128], B=W2 from GLOBAL, Cn=8 ----
        {
            float C[8][4];
            {
                float4 b20 = *(const float4*)(smem + OFF_B2 + nc2);
                float4 b21 = *(const float4*)(smem + OFF_B2 + nc2 + 4);
                float bv[8] = {b20.x, b20.y, b20.z, b20.w, b21.x, b21.y, b21.z, b21.w};
#pragma unroll
                for (int j = 0; j < 8; ++j)
#pragma unroll
                    for (int m = 0; m < 4; ++m) C[j][m] = bv[j];
            }
#pragma unroll 4
            for (int k = 0; k < 64; ++k) {
                float4 a = *(const float4*)(hT + k * 132 + mm);
                float av[4] = {a.x, a.y, a.z, a.w};
                float4 B0 = *(const float4*)(W2 + k * 128 + nc2);
                float4 B1 = *(const float4*)(W2 + k * 128 + nc2 + 4);
                float bs[8] = {B0.x, B0.y, B0.z, B0.w, B1.x, B1.y, B1.z, B1.w};
#pragma unroll
                for (int j = 0; j < 8; ++j)
#pragma unroll
                    for (int m = 0; m < 4; ++m)
                        C[j][m] = fmaf(av[m], bs[j], C[j][m]);
            }
            // epilogue: multiply by rndata[src], scatter-add into sacc
#pragma unroll
            for (int m = 0; m < 4; ++m) {
                int e = ebase + mm + m;
                if (e < e1) {
                    int d = dsts[e], s = srcs[e];
                    float4 r0 = *(const float4*)(rndata + (size_t)s * 128 + nc2);
                    float4 r1 = *(const float4*)(rndata + (size_t)s * 128 + nc2 + 4);
                    float rs[8] = {r0.x, r0.y, r0.z, r0.w, r1.x, r1.y, r1.z, r1.w};
                    float* ac = &sacc[(d - q0) * 129 + nc2];
#pragma unroll
                    for (int j = 0; j < 8; ++j)
                        atomicAdd(&ac[j], C[j][m] * rs[j]);
                }
            }
        }
        __syncthreads();  // hT/einT safe to overwrite; sacc updates visible
    }
    __syncthreads();  // ntiles==0 path: sacc zero-init visible

    if (!FUSED_PROJ) {
        // write per-query mean to global agg (coalesced across c)
        for (int idx = tid; idx < QB * 128; idx += BLOCK) {
            int ql = idx >> 7, c = idx & 127;
            int q  = q0 + ql;
            if (q < qend) {
                float deg = (float)(start[q + 1] - start[q]);
                agg[(size_t)q * 128 + c] = sacc[ql * 129 + c] / fmaxf(deg, 1.f);
            }
        }
    } else {
        if (tid < QB) {
            int q = q0 + tid;
            if (q < nq) {
                float deg = (float)(start[q + 1] - start[q]);
                float inv = 1.0f / fmaxf(deg, 1.f);
                const float* aq = &sacc[tid * 129];
                float o0 = pb1[0], o1 = pb1[1], o2 = pb1[2], o3 = pb1[3];
#pragma unroll 1
                for (int jj = 0; jj < 256; jj += 8) {
                    float acc[8];
#pragma unroll
                    for (int u = 0; u < 8; ++u) acc[u] = pb0[jj + u];
#pragma unroll
                    for (int i = 0; i < 128; ++i) {
                        float av = aq[i] * inv;
#pragma unroll
                        for (int u = 0; u < 8; ++u)
                            acc[u] = fmaf(av, P0[i * 256 + jj + u], acc[u]);
                    }
#pragma unroll
                    for (int u = 0; u < 8; ++u) {
                        float h = gelu_f(acc[u]);
                        o0 = fmaf(h, P1[(jj + u) * 4 + 0], o0);
                        o1 = fmaf(h, P1[(jj + u) * 4 + 1], o1);
                        o2 = fmaf(h, P1[(jj + u) * 4 + 2], o2);
                        o3 = fmaf(h, P1[(jj + u) * 4 + 3], o3);
                    }
                }
                float4* o4 = (float4*)(out + (size_t)q * 4);
                *o4 = make_float4(o0, o1, o2, o3);
            }
        }
    }
}

// ---------- projection: P0 column-chunked through LDS (r10 proven) ----------

__global__ __launch_bounds__(256) void proj_kernel(
    const float* __restrict__ agg,      // [NQ,128] mean
    const float* __restrict__ P0, const float* __restrict__ pb0,
    const float* __restrict__ P1, const float* __restrict__ pb1,
    float* __restrict__ out, int nq)
{
    __shared__ float sm[8192 + 1024 + 256 + 4];
    float* sP0c = sm;             // [128][64]
    float* sP1  = sm + 8192;      // [256][4]
    float* spb0 = sm + 9216;      // [256]
    float* spb1 = sm + 9472;      // [4]

    const int tid = threadIdx.x;
    {
        float4* s4 = (float4*)sP1;
        const float4* g4 = (const float4*)P1;
        if (tid < 256) s4[tid] = g4[tid];
        if (tid < 64) ((float4*)spb0)[tid] = ((const float4*)pb0)[tid];
        if (tid == 0) ((float4*)spb1)[0] = ((const float4*)pb1)[0];
    }

    const int q = blockIdx.x * blockDim.x + tid;
    float a[128];
    if (q < nq) {
        const float4* ag4 = (const float4*)(agg + (size_t)q * 128);
#pragma unroll
        for (int i = 0; i < 32; ++i) {
            float4 v = ag4[i];
            a[4 * i + 0] = v.x; a[4 * i + 1] = v.y;
            a[4 * i + 2] = v.z; a[4 * i + 3] = v.w;
        }
    }

    float o0 = 0.f, o1 = 0.f, o2 = 0.f, o3 = 0.f;

#pragma unroll 1
    for (int c = 0; c < 4; ++c) {
        __syncthreads();
        {
            float4* s4 = (float4*)sP0c;
            const float4* g4 = (const float4*)P0;  // [128][64 f4]
            for (int idx = tid; idx < 2048; idx += 256) {
                int row = idx >> 4, col4 = idx & 15;
                s4[idx] = g4[row * 64 + c * 16 + col4];
            }
        }
        __syncthreads();
        if (q < nq) {
            if (c == 0) { o0 = spb1[0]; o1 = spb1[1]; o2 = spb1[2]; o3 = spb1[3]; }
#pragma unroll 1
            for (int jjb = 0; jjb < 8; ++jjb) {
                int jl = jjb * 8;
                float acc[8];
#pragma unroll
                for (int u = 0; u < 8; ++u) acc[u] = spb0[c * 64 + jl + u];
#pragma unroll 2
                for (int i = 0; i < 128; ++i) {
                    float av = a[i];
                    float4 w0v = *(const float4*)(sP0c + i * 64 + jl);
                    float4 w1v = *(const float4*)(sP0c + i * 64 + jl + 4);
                    acc[0] = fmaf(av, w0v.x, acc[0]);
                    acc[1] = fmaf(av, w0v.y, acc[1]);
                    acc[2] = fmaf(av, w0v.z, acc[2]);
                    acc[3] = fmaf(av, w0v.w, acc[3]);
                    acc[4] = fmaf(av, w1v.x, acc[4]);
                    acc[5] = fmaf(av, w1v.y, acc[5]);
                    acc[6] = fmaf(av, w1v.z, acc[6]);
                    acc[7] = fmaf(av, w1v.w, acc[7]);
                }
#pragma unroll
                for (int u = 0; u < 8; ++u) {
                    float h = gelu_f(acc[u]);
                    const float* p1r = sP1 + (c * 64 + jl + u) * 4;
                    o0 = fmaf(h, p1r[0], o0);
                    o1 = fmaf(h, p1r[1], o1);
                    o2 = fmaf(h, p1r[2], o2);
                    o3 = fmaf(h, p1r[3], o3);
                }
            }
        }
    }
    if (q < nq) {
        float4* o4 = (float4*)(out + (size_t)q * 4);
        *o4 = make_float4(o0, o1, o2, o3);
    }
}

extern "C" void kernel_launch(void* const* d_in, const int* in_sizes, int n_in,
                              void* d_out, int out_size, void* d_ws, size_t ws_size,
                              hipStream_t stream)
{
    const float* rndata = (const float*)d_in[0];
    const float* qpos   = (const float*)d_in[1];
    const float* lpos   = (const float*)d_in[2];
    const int*   dst    = (const int*)d_in[3];
    const int*   src    = (const int*)d_in[4];
    const float* W0  = (const float*)d_in[5];
    const float* b0  = (const float*)d_in[6];
    const float* W1  = (const float*)d_in[7];
    const float* b1  = (const float*)d_in[8];
    const float* W2  = (const float*)d_in[9];
    const float* b2  = (const float*)d_in[10];
    const float* P0  = (const float*)d_in[11];
    const float* pb0 = (const float*)d_in[12];
    const float* P1  = (const float*)d_in[13];
    const float* pb1 = (const float*)d_in[14];

    int nq = in_sizes[1] / 3;
    int E  = in_sizes[3];

    // ws layout: [agg nq*128 (path A)] [hist] [cursor] [start] [dsts] [srcs]
    size_t agg_bytes  = (size_t)nq * 128 * sizeof(float);
    size_t sort_bytes = 0;
    {
        size_t o = 0;
        o += ((size_t)nq * sizeof(int) + 15) & ~(size_t)15;
        o += ((size_t)nq * sizeof(int) + 15) & ~(size_t)15;
        o += ((size_t)(nq + 1) * sizeof(int) + 15) & ~(size_t)15;
        o += ((size_t)E * sizeof(int) + 15) & ~(size_t)15;
        o += ((size_t)E * sizeof(int) + 15) & ~(size_t)15;
        sort_bytes = o;
    }
    bool path_a = (agg_bytes + sort_bytes) <= ws_size;

    size_t off = path_a ? agg_bytes : 0;
    auto alloc = [&](size_t bytes) {
        void* p = (char*)d_ws + off;
        off += (bytes + 15) & ~(size_t)15;
        return p;
    };
    float* agg   = (float*)d_ws;  // path A only
    int* hist    = (int*)alloc((size_t)nq * sizeof(int));
    int* cursor  = (int*)alloc((size_t)nq * sizeof(int));
    int* start   = (int*)alloc((size_t)(nq + 1) * sizeof(int));
    int* dsts    = (int*)alloc((size_t)E * sizeof(int));
    int* srcs    = (int*)alloc((size_t)E * sizeof(int));

    size_t histpad = ((size_t)nq * sizeof(int) + 15) & ~(size_t)15;
    hipMemsetAsync(hist, 0, 2 * histpad, stream);

    hist_kernel<<<(E + 255) / 256, 256, 0, stream>>>(dst, hist, E);
    scan_kernel<<<1, 1024, 0, stream>>>(hist, start, nq);
    scatter_kernel<<<(E + 255) / 256, 256, 0, stream>>>(dst, src, start, cursor, dsts, srcs, E);

    constexpr int    QB   = 24;
    constexpr size_t SMEM = (size_t)(9880 + QB * 129) * 4;  // 51,904 B -> 3 blocks/CU
    int nb = (nq + QB - 1) / QB;

    if (path_a) {
        fused_kernel<QB, false><<<nb, BLOCK, SMEM, stream>>>(
            rndata, qpos, lpos, dsts, srcs, start,
            W0, b0, W1, b1, W2, b2, P0, pb0, P1, pb1, agg, nullptr, nq);
        proj_kernel<<<(nq + 255) / 256, 256, 0, stream>>>(
            agg, P0, pb0, P1, pb1, (float*)d_out, nq);
    } else {
        fused_kernel<QB, true><<<nb, BLOCK, SMEM, stream>>>(
            rndata, qpos, lpos, dsts, srcs, start,
            W0, b0, W1, b1, W2, b2, P0, pb0, P1, pb1, nullptr, (float*)d_out, nq);
    }
}

// Round 12
// 1728.241 us; speedup vs baseline: 1.5530x; 1.2783x over previous
//
#include <hip/hip_runtime.h>

// GNODecoder round 12:
// (1) REVERT proj to r7/r9's plain 256-thread kernel -- the r10 chunked-LDS
//     proj was a ~500 us regression (770 us vs 270 us residual).
// (2) fused: M=64 edge tiles -> hT[64][68] 17 KB, total LDS 33,984 B ->
//     4 blocks/CU = 32 waves (r11 measured 42% occupancy at 51.9 KB; all
//     pipe floors were 4-6x below measured = latency-bound). Mapping:
//     8 waves: L0/L1 n=w*8+ng*2 (Cn=2), L2 n=w*16+ng*4 (Cn=4), Cm=4.
//     Weights B from global/L1 (r11 proven). ~50 VGPR -> 8 waves/SIMD legal.

#define BLOCK 512

// LDS float offsets
#define OFF_W0   0      // [6][64] = 384
#define OFF_B0   384    // [64]
#define OFF_B1   448    // [64]
#define OFF_B2   512    // [128]
#define OFF_EIN  640    // [6][68] = 408
#define OFF_HT   1048   // [64][68] = 4352 (h0 then h1)
#define OFF_SACC 5400   // [QB*129]

__device__ __forceinline__ float gelu_f(float x) {
    // jax.nn.gelu default (approximate=True, tanh form)
    float x3 = x * x * x;
    float t  = 0.7978845608028654f * fmaf(0.044715f, x3, x);
    float e  = __expf(2.0f * t);
    float r  = __builtin_amdgcn_rcpf(e + 1.0f);
    return 0.5f * x * (1.0f + (1.0f - 2.0f * r));
}

// ---------- sort machinery (proven) ----------

__global__ void hist_kernel(const int* __restrict__ dst, int* __restrict__ hist, int E) {
    int e = blockIdx.x * blockDim.x + threadIdx.x;
    if (e < E) atomicAdd(&hist[dst[e]], 1);
}

__global__ __launch_bounds__(1024) void scan_kernel(const int* __restrict__ hist,
                                                    int* __restrict__ start, int n) {
    __shared__ int wsum[16];
    __shared__ int woff[16];
    int tid = threadIdx.x;
    int lane = tid & 63, wid = tid >> 6;
    int carry = 0;  // meaningful on tid 0 only
    for (int base = 0; base < n; base += 1024) {
        int i = base + tid;
        int v = (i < n) ? hist[i] : 0;
        int incl = v;
#pragma unroll
        for (int off = 1; off < 64; off <<= 1) {
            int t = __shfl_up(incl, off, 64);
            if (lane >= off) incl += t;
        }
        if (lane == 63) wsum[wid] = incl;
        __syncthreads();
        if (tid == 0) {
            int acc = carry;
#pragma unroll
            for (int w = 0; w < 16; ++w) { woff[w] = acc; acc += wsum[w]; }
            carry = acc;
        }
        __syncthreads();
        if (i < n) start[i] = woff[wid] + incl - v;
        __syncthreads();
    }
    if (threadIdx.x == 0) start[n] = carry;
}

__global__ void scatter_kernel(const int* __restrict__ dst, const int* __restrict__ src,
                               const int* __restrict__ start, int* __restrict__ cursor,
                               int* __restrict__ dsts, int* __restrict__ srcs, int E) {
    int e = blockIdx.x * blockDim.x + threadIdx.x;
    if (e >= E) return;
    int d = dst[e];
    int pos = start[d] + atomicAdd(&cursor[d], 1);
    dsts[pos] = d;
    srcs[pos] = src[e];
}

// ---------- fused: M=64 tiled GEMM, weights-from-global ----------

template <int QB, bool FUSED_PROJ>
__global__ __launch_bounds__(BLOCK) void fused_kernel(
    const float* __restrict__ rndata,   // [NL,128]
    const float* __restrict__ qpos,     // [NQ,3]
    const float* __restrict__ lpos,     // [NL,3]
    const int*   __restrict__ dsts,     // [E] sorted by dst
    const int*   __restrict__ srcs,     // [E]
    const int*   __restrict__ start,    // [NQ+1]
    const float* __restrict__ W0, const float* __restrict__ b0,
    const float* __restrict__ W1, const float* __restrict__ b1,
    const float* __restrict__ W2, const float* __restrict__ b2,
    const float* __restrict__ P0, const float* __restrict__ pb0,
    const float* __restrict__ P1, const float* __restrict__ pb1,
    float* __restrict__ agg,            // [NQ,128] mean (path A)
    float* __restrict__ out,            // [NQ,4]   (FUSED_PROJ)
    int nq)
{
    extern __shared__ float smem[];
    const int tid = threadIdx.x;

    // ---- stage small weights (W0 + biases); W1/W2 stay in global/L1 ----
    if (tid < 96)       ((float4*)(smem + OFF_W0))[tid]       = ((const float4*)W0)[tid];
    else if (tid < 112) ((float4*)(smem + OFF_B0))[tid - 96]  = ((const float4*)b0)[tid - 96];
    else if (tid < 128) ((float4*)(smem + OFF_B1))[tid - 112] = ((const float4*)b1)[tid - 112];
    else if (tid < 160) ((float4*)(smem + OFF_B2))[tid - 128] = ((const float4*)b2)[tid - 128];
    for (int i = tid; i < QB * 129; i += BLOCK) smem[OFF_SACC + i] = 0.f;

    float* einT = smem + OFF_EIN;   // [6][68]
    float* hT   = smem + OFF_HT;    // [64][68]
    float* sacc = smem + OFF_SACC;  // [QB][129]

    const int q0   = blockIdx.x * QB;
    const int qend = min(q0 + QB, nq);
    const int e0 = start[q0], e1 = start[qend];
    const int ntiles = (e1 - e0 + 63) >> 6;

    const int w = tid >> 6, lane = tid & 63;
    const int mg = lane & 15, ng = lane >> 4;
    const int mm  = mg * 4;                  // 4 m-rows (edges) per lane
    const int nc1 = w * 8 + ng * 2;          // L0/L1 n-base (N=64)
    const int nc2 = w * 16 + ng * 4;         // L2 n-base (N=128)

    for (int t = 0; t < ntiles; ++t) {
        const int ebase = e0 + (t << 6);

        // ---- gather einT (threads 0..63, one edge each) ----
        if (tid < 64) {
            int e = ebase + tid;
            if (e < e1) {
                int d = dsts[e], s = srcs[e];
                einT[0 * 68 + tid] = qpos[d * 3 + 0];
                einT[1 * 68 + tid] = qpos[d * 3 + 1];
                einT[2 * 68 + tid] = qpos[d * 3 + 2];
                einT[3 * 68 + tid] = lpos[s * 3 + 0];
                einT[4 * 68 + tid] = lpos[s * 3 + 1];
                einT[5 * 68 + tid] = lpos[s * 3 + 2];
            } else {
#pragma unroll
                for (int c = 0; c < 6; ++c) einT[c * 68 + tid] = 0.f;
            }
        }
        __syncthreads();  // einT ready (first iter: staging too)

        // ---- L0: [64,6] x [6,64] -> hT (h0), B from LDS, Cn=2 ----
        {
            float C[2][4];
            float2 bb = *(const float2*)(smem + OFF_B0 + nc1);
            float bv[2] = {bb.x, bb.y};
#pragma unroll
            for (int j = 0; j < 2; ++j)
#pragma unroll
                for (int m = 0; m < 4; ++m) C[j][m] = bv[j];
#pragma unroll
            for (int k = 0; k < 6; ++k) {
                float4 a = *(const float4*)(einT + k * 68 + mm);
                float av[4] = {a.x, a.y, a.z, a.w};
                float2 B = *(const float2*)(smem + OFF_W0 + k * 64 + nc1);
                float bs[2] = {B.x, B.y};
#pragma unroll
                for (int j = 0; j < 2; ++j)
#pragma unroll
                    for (int m = 0; m < 4; ++m)
                        C[j][m] = fmaf(av[m], bs[j], C[j][m]);
            }
#pragma unroll
            for (int j = 0; j < 2; ++j) {
                float4 o = make_float4(gelu_f(C[j][0]), gelu_f(C[j][1]),
                                       gelu_f(C[j][2]), gelu_f(C[j][3]));
                *(float4*)(hT + (nc1 + j) * 68 + mm) = o;
            }
        }
        __syncthreads();  // h0 ready

        // ---- L1: [64,64] x [64,64], B=W1 from GLOBAL, C in regs ----
        float C1[2][4];
        {
            float2 bb = *(const float2*)(smem + OFF_B1 + nc1);
            float bv[2] = {bb.x, bb.y};
#pragma unroll
            for (int j = 0; j < 2; ++j)
#pragma unroll
                for (int m = 0; m < 4; ++m) C1[j][m] = bv[j];
#pragma unroll 4
            for (int k = 0; k < 64; ++k) {
                float4 a = *(const float4*)(hT + k * 68 + mm);
                float av[4] = {a.x, a.y, a.z, a.w};
                float2 B = *(const float2*)(W1 + k * 64 + nc1);
                float bs[2] = {B.x, B.y};
#pragma unroll
                for (int j = 0; j < 2; ++j)
#pragma unroll
                    for (int m = 0; m < 4; ++m)
                        C1[j][m] = fmaf(av[m], bs[j], C1[j][m]);
            }
        }
        __syncthreads();  // all waves done READING h0

        // write h1 = gelu(C1) over hT
#pragma unroll
        for (int j = 0; j < 2; ++j) {
            float4 o = make_float4(gelu_f(C1[j][0]), gelu_f(C1[j][1]),
                                   gelu_f(C1[j][2]), gelu_f(C1[j][3]));
            *(float4*)(hT + (nc1 + j) * 68 + mm) = o;
        }
        __syncthreads();  // h1 ready

        // ---- L2: [64,64] x [64,128], B=W2 from GLOBAL, Cn=4 ----
        {
            float C[4][4];
            {
                float4 bb = *(const float4*)(smem + OFF_B2 + nc2);
                float bv[4] = {bb.x, bb.y, bb.z, bb.w};
#pragma unroll
                for (int j = 0; j < 4; ++j)
#pragma unroll
                    for (int m = 0; m < 4; ++m) C[j][m] = bv[j];
            }
#pragma unroll 4
            for (int k = 0; k < 64; ++k) {
                float4 a = *(const float4*)(hT + k * 68 + mm);
                float av[4] = {a.x, a.y, a.z, a.w};
                float4 B = *(const float4*)(W2 + k * 128 + nc2);
                float bs[4] = {B.x, B.y, B.z, B.w};
#pragma unroll
                for (int j = 0; j < 4; ++j)
#pragma unroll
                    for (int m = 0; m < 4; ++m)
                        C[j][m] = fmaf(av[m], bs[j], C[j][m]);
            }
            // epilogue: multiply by rndata[src], scatter-add into sacc
#pragma unroll
            for (int m = 0; m < 4; ++m) {
                int e = ebase + mm + m;
                if (e < e1) {
                    int d = dsts[e], s = srcs[e];
                    float4 r = *(const float4*)(rndata + (size_t)s * 128 + nc2);
                    float rs[4] = {r.x, r.y, r.z, r.w};
                    float* ac = &sacc[(d - q0) * 129 + nc2];
#pragma unroll
                    for (int j = 0; j < 4; ++j)
                        atomicAdd(&ac[j], C[j][m] * rs[j]);
                }
            }
        }
        __syncthreads();  // hT/einT safe to overwrite; sacc updates visible
    }
    __syncthreads();  // ntiles==0 path: sacc zero-init visible

    if (!FUSED_PROJ) {
        // write per-query mean to global agg (coalesced across c)
        for (int idx = tid; idx < QB * 128; idx += BLOCK) {
            int ql = idx >> 7, c = idx & 127;
            int q  = q0 + ql;
            if (q < qend) {
                float deg = (float)(start[q + 1] - start[q]);
                agg[(size_t)q * 128 + c] = sacc[ql * 129 + c] / fmaxf(deg, 1.f);
            }
        }
    } else {
        if (tid < QB) {
            int q = q0 + tid;
            if (q < nq) {
                float deg = (float)(start[q + 1] - start[q]);
                float inv = 1.0f / fmaxf(deg, 1.f);
                const float* aq = &sacc[tid * 129];
                float o0 = pb1[0], o1 = pb1[1], o2 = pb1[2], o3 = pb1[3];
#pragma unroll 1
                for (int jj = 0; jj < 256; jj += 8) {
                    float acc[8];
#pragma unroll
                    for (int u = 0; u < 8; ++u) acc[u] = pb0[jj + u];
#pragma unroll
                    for (int i = 0; i < 128; ++i) {
                        float av = aq[i] * inv;
#pragma unroll
                        for (int u = 0; u < 8; ++u)
                            acc[u] = fmaf(av, P0[i * 256 + jj + u], acc[u]);
                    }
#pragma unroll
                    for (int u = 0; u < 8; ++u) {
                        float h = gelu_f(acc[u]);
                        o0 = fmaf(h, P1[(jj + u) * 4 + 0], o0);
                        o1 = fmaf(h, P1[(jj + u) * 4 + 1], o1);
                        o2 = fmaf(h, P1[(jj + u) * 4 + 2], o2);
                        o3 = fmaf(h, P1[(jj + u) * 4 + 3], o3);
                    }
                }
                float4* o4 = (float4*)(out + (size_t)q * 4);
                *o4 = make_float4(o0, o1, o2, o3);
            }
        }
    }
}

// ---------- projection: plain r7/r9 kernel (proven ~270 us) ----------

__global__ __launch_bounds__(256) void proj_kernel(
    const float* __restrict__ agg,      // [NQ,128] mean
    const float* __restrict__ P0, const float* __restrict__ pb0,
    const float* __restrict__ P1, const float* __restrict__ pb1,
    float* __restrict__ out, int nq)
{
    int q = blockIdx.x * blockDim.x + threadIdx.x;
    if (q >= nq) return;

    float a[128];
    const float4* ag4 = (const float4*)(agg + (size_t)q * 128);
#pragma unroll
    for (int i = 0; i < 32; ++i) {
        float4 v = ag4[i];
        a[4 * i + 0] = v.x; a[4 * i + 1] = v.y;
        a[4 * i + 2] = v.z; a[4 * i + 3] = v.w;
    }

    float o0 = pb1[0], o1 = pb1[1], o2 = pb1[2], o3 = pb1[3];
#pragma unroll 1
    for (int jj = 0; jj < 256; jj += 8) {
        float acc[8];
#pragma unroll
        for (int u = 0; u < 8; ++u) acc[u] = pb0[jj + u];
#pragma unroll
        for (int i = 0; i < 128; ++i) {
            float av = a[i];
#pragma unroll
            for (int u = 0; u < 8; ++u)
                acc[u] = fmaf(av, P0[i * 256 + jj + u], acc[u]);
        }
#pragma unroll
        for (int u = 0; u < 8; ++u) {
            float h = gelu_f(acc[u]);
            o0 = fmaf(h, P1[(jj + u) * 4 + 0], o0);
            o1 = fmaf(h, P1[(jj + u) * 4 + 1], o1);
            o2 = fmaf(h, P1[(jj + u) * 4 + 2], o2);
            o3 = fmaf(h, P1[(jj + u) * 4 + 3], o3);
        }
    }
    float4* o4 = (float4*)(out + (size_t)q * 4);
    *o4 = make_float4(o0, o1, o2, o3);
}

extern "C" void kernel_launch(void* const* d_in, const int* in_sizes, int n_in,
                              void* d_out, int out_size, void* d_ws, size_t ws_size,
                              hipStream_t stream)
{
    const float* rndata = (const float*)d_in[0];
    const float* qpos   = (const float*)d_in[1];
    const float* lpos   = (const float*)d_in[2];
    const int*   dst    = (const int*)d_in[3];
    const int*   src    = (const int*)d_in[4];
    const float* W0  = (const float*)d_in[5];
    const float* b0  = (const float*)d_in[6];
    const float* W1  = (const float*)d_in[7];
    const float* b1  = (const float*)d_in[8];
    const float* W2  = (const float*)d_in[9];
    const float* b2  = (const float*)d_in[10];
    const float* P0  = (const float*)d_in[11];
    const float* pb0 = (const float*)d_in[12];
    const float* P1  = (const float*)d_in[13];
    const float* pb1 = (const float*)d_in[14];

    int nq = in_sizes[1] / 3;
    int E  = in_sizes[3];

    // ws layout: [agg nq*128 (path A)] [hist] [cursor] [start] [dsts] [srcs]
    size_t agg_bytes  = (size_t)nq * 128 * sizeof(float);
    size_t sort_bytes = 0;
    {
        size_t o = 0;
        o += ((size_t)nq * sizeof(int) + 15) & ~(size_t)15;
        o += ((size_t)nq * sizeof(int) + 15) & ~(size_t)15;
        o += ((size_t)(nq + 1) * sizeof(int) + 15) & ~(size_t)15;
        o += ((size_t)E * sizeof(int) + 15) & ~(size_t)15;
        o += ((size_t)E * sizeof(int) + 15) & ~(size_t)15;
        sort_bytes = o;
    }
    bool path_a = (agg_bytes + sort_bytes) <= ws_size;

    size_t off = path_a ? agg_bytes : 0;
    auto alloc = [&](size_t bytes) {
        void* p = (char*)d_ws + off;
        off += (bytes + 15) & ~(size_t)15;
        return p;
    };
    float* agg   = (float*)d_ws;  // path A only
    int* hist    = (int*)alloc((size_t)nq * sizeof(int));
    int* cursor  = (int*)alloc((size_t)nq * sizeof(int));
    int* start   = (int*)alloc((size_t)(nq + 1) * sizeof(int));
    int* dsts    = (int*)alloc((size_t)E * sizeof(int));
    int* srcs    = (int*)alloc((size_t)E * sizeof(int));

    size_t histpad = ((size_t)nq * sizeof(int) + 15) & ~(size_t)15;
    hipMemsetAsync(hist, 0, 2 * histpad, stream);

    hist_kernel<<<(E + 255) / 256, 256, 0, stream>>>(dst, hist, E);
    scan_kernel<<<1, 1024, 0, stream>>>(hist, start, nq);
    scatter_kernel<<<(E + 255) / 256, 256, 0, stream>>>(dst, src, start, cursor, dsts, srcs, E);

    constexpr int    QB   = 24;
    constexpr size_t SMEM = (size_t)(5400 + QB * 129) * 4;  // 33,984 B -> 4 blocks/CU
    int nb = (nq + QB - 1) / QB;

    if (path_a) {
        fused_kernel<QB, false><<<nb, BLOCK, SMEM, stream>>>(
            rndata, qpos, lpos, dsts, srcs, start,
            W0, b0, W1, b1, W2, b2, P0, pb0, P1, pb1, agg, nullptr, nq);
        proj_kernel<<<(nq + 255) / 256, 256, 0, stream>>>(
            agg, P0, pb0, P1, pb1, (float*)d_out, nq);
    } else {
        fused_kernel<QB, true><<<nb, BLOCK, SMEM, stream>>>(
            rndata, qpos, lpos, dsts, srcs, start,
            W0, b0, W1, b1, W2, b2, P0, pb0, P1, pb1, nullptr, (float*)d_out, nq);
    }
}

// Round 13
// 1574.445 us; speedup vs baseline: 1.7047x; 1.0977x over previous
//
#include <hip/hip_runtime.h>

// GNODecoder round 13: r10-r12 pinned VALUBusy ~21% across 42-63% occupancy
// -> per-wave ILP-bound (k-loop: 16 FMAs per ~350cyc load window). Fix:
// BLOCK=256, M=128 tile, Cm=8 via split-M (rows mg*4 and 64+mg*4: both
// A-b128s 2-way free), Cn=4 (L1) / Cn=8 (L2): 32-64 indep FMAs per k-step,
// 2-4x issue per load window. VGPR ~105 fits the proven 128 cap @256thr.
// Weights B from global/L1 (r11). LDS 51.9 KB QB=24 (occupancy proven
// irrelevant past ~12 waves/CU). proj = plain r7/r9 kernel (proven).

#define BLOCK 256

// LDS float offsets
#define OFF_W0   0      // [6][64] = 384
#define OFF_B0   384    // [64]
#define OFF_B1   448    // [64]
#define OFF_B2   512    // [128]
#define OFF_EIN  640    // [6][132] = 792
#define OFF_HT   1432   // [64][132] = 8448 (h0 then h1)
#define OFF_SACC 9880   // [QB*129]

__device__ __forceinline__ float gelu_f(float x) {
    // jax.nn.gelu default (approximate=True, tanh form)
    float x3 = x * x * x;
    float t  = 0.7978845608028654f * fmaf(0.044715f, x3, x);
    float e  = __expf(2.0f * t);
    float r  = __builtin_amdgcn_rcpf(e + 1.0f);
    return 0.5f * x * (1.0f + (1.0f - 2.0f * r));
}

// ---------- sort machinery (proven) ----------

__global__ void hist_kernel(const int* __restrict__ dst, int* __restrict__ hist, int E) {
    int e = blockIdx.x * blockDim.x + threadIdx.x;
    if (e < E) atomicAdd(&hist[dst[e]], 1);
}

__global__ __launch_bounds__(1024) void scan_kernel(const int* __restrict__ hist,
                                                    int* __restrict__ start, int n) {
    __shared__ int wsum[16];
    __shared__ int woff[16];
    int tid = threadIdx.x;
    int lane = tid & 63, wid = tid >> 6;
    int carry = 0;  // meaningful on tid 0 only
    for (int base = 0; base < n; base += 1024) {
        int i = base + tid;
        int v = (i < n) ? hist[i] : 0;
        int incl = v;
#pragma unroll
        for (int off = 1; off < 64; off <<= 1) {
            int t = __shfl_up(incl, off, 64);
            if (lane >= off) incl += t;
        }
        if (lane == 63) wsum[wid] = incl;
        __syncthreads();
        if (tid == 0) {
            int acc = carry;
#pragma unroll
            for (int w = 0; w < 16; ++w) { woff[w] = acc; acc += wsum[w]; }
            carry = acc;
        }
        __syncthreads();
        if (i < n) start[i] = woff[wid] + incl - v;
        __syncthreads();
    }
    if (threadIdx.x == 0) start[n] = carry;
}

__global__ void scatter_kernel(const int* __restrict__ dst, const int* __restrict__ src,
                               const int* __restrict__ start, int* __restrict__ cursor,
                               int* __restrict__ dsts, int* __restrict__ srcs, int E) {
    int e = blockIdx.x * blockDim.x + threadIdx.x;
    if (e >= E) return;
    int d = dst[e];
    int pos = start[d] + atomicAdd(&cursor[d], 1);
    dsts[pos] = d;
    srcs[pos] = src[e];
}

// ---------- fused: M=128 tiled GEMM, Cm=8 split-M, weights-from-global ----------

template <int QB, bool FUSED_PROJ>
__global__ __launch_bounds__(BLOCK) void fused_kernel(
    const float* __restrict__ rndata,   // [NL,128]
    const float* __restrict__ qpos,     // [NQ,3]
    const float* __restrict__ lpos,     // [NL,3]
    const int*   __restrict__ dsts,     // [E] sorted by dst
    const int*   __restrict__ srcs,     // [E]
    const int*   __restrict__ start,    // [NQ+1]
    const float* __restrict__ W0, const float* __restrict__ b0,
    const float* __restrict__ W1, const float* __restrict__ b1,
    const float* __restrict__ W2, const float* __restrict__ b2,
    const float* __restrict__ P0, const float* __restrict__ pb0,
    const float* __restrict__ P1, const float* __restrict__ pb1,
    float* __restrict__ agg,            // [NQ,128] mean (path A)
    float* __restrict__ out,            // [NQ,4]   (FUSED_PROJ)
    int nq)
{
    extern __shared__ float smem[];
    const int tid = threadIdx.x;

    // ---- stage small weights (W0 + biases); W1/W2 stay in global/L1 ----
    if (tid < 96)       ((float4*)(smem + OFF_W0))[tid]       = ((const float4*)W0)[tid];
    else if (tid < 112) ((float4*)(smem + OFF_B0))[tid - 96]  = ((const float4*)b0)[tid - 96];
    else if (tid < 128) ((float4*)(smem + OFF_B1))[tid - 112] = ((const float4*)b1)[tid - 112];
    else if (tid < 160) ((float4*)(smem + OFF_B2))[tid - 128] = ((const float4*)b2)[tid - 128];
    for (int i = tid; i < QB * 129; i += BLOCK) smem[OFF_SACC + i] = 0.f;

    float* einT = smem + OFF_EIN;   // [6][132]
    float* hT   = smem + OFF_HT;    // [64][132]
    float* sacc = smem + OFF_SACC;  // [QB][129]

    const int q0   = blockIdx.x * QB;
    const int qend = min(q0 + QB, nq);
    const int e0 = start[q0], e1 = start[qend];
    const int ntiles = (e1 - e0 + 127) >> 7;

    const int w = tid >> 6, lane = tid & 63;
    const int mg = lane & 15, ng = lane >> 4;
    const int mA  = mg * 4;              // rows mA..mA+3 and 64+mA..64+mA+3
    const int nc1 = w * 16 + ng * 4;     // L0/L1 n-base (N=64)
    const int nc2 = w * 32 + ng * 8;     // L2 n-base (N=128)

    for (int t = 0; t < ntiles; ++t) {
        const int ebase = e0 + (t << 7);

        // ---- gather einT (threads 0..127, one edge each) ----
        if (tid < 128) {
            int e = ebase + tid;
            if (e < e1) {
                int d = dsts[e], s = srcs[e];
                einT[0 * 132 + tid] = qpos[d * 3 + 0];
                einT[1 * 132 + tid] = qpos[d * 3 + 1];
                einT[2 * 132 + tid] = qpos[d * 3 + 2];
                einT[3 * 132 + tid] = lpos[s * 3 + 0];
                einT[4 * 132 + tid] = lpos[s * 3 + 1];
                einT[5 * 132 + tid] = lpos[s * 3 + 2];
            } else {
#pragma unroll
                for (int c = 0; c < 6; ++c) einT[c * 132 + tid] = 0.f;
            }
        }
        __syncthreads();  // einT ready (first iter: staging too)

        // ---- L0: [128,6] x [6,64] -> hT (h0), B from LDS, Cn=4/Cm=8 ----
        {
            float C[4][8];
            float4 bb = *(const float4*)(smem + OFF_B0 + nc1);
            float bv[4] = {bb.x, bb.y, bb.z, bb.w};
#pragma unroll
            for (int j = 0; j < 4; ++j)
#pragma unroll
                for (int m = 0; m < 8; ++m) C[j][m] = bv[j];
#pragma unroll
            for (int k = 0; k < 6; ++k) {
                float4 a0 = *(const float4*)(einT + k * 132 + mA);
                float4 a1 = *(const float4*)(einT + k * 132 + 64 + mA);
                float av[8] = {a0.x, a0.y, a0.z, a0.w, a1.x, a1.y, a1.z, a1.w};
                float4 B = *(const float4*)(smem + OFF_W0 + k * 64 + nc1);
                float bs[4] = {B.x, B.y, B.z, B.w};
#pragma unroll
                for (int j = 0; j < 4; ++j)
#pragma unroll
                    for (int m = 0; m < 8; ++m)
                        C[j][m] = fmaf(av[m], bs[j], C[j][m]);
            }
#pragma unroll
            for (int j = 0; j < 4; ++j) {
                float4 o0 = make_float4(gelu_f(C[j][0]), gelu_f(C[j][1]),
                                        gelu_f(C[j][2]), gelu_f(C[j][3]));
                float4 o1 = make_float4(gelu_f(C[j][4]), gelu_f(C[j][5]),
                                        gelu_f(C[j][6]), gelu_f(C[j][7]));
                *(float4*)(hT + (nc1 + j) * 132 + mA) = o0;
                *(float4*)(hT + (nc1 + j) * 132 + 64 + mA) = o1;
            }
        }
        __syncthreads();  // h0 ready

        // ---- L1: [128,64] x [64,64], B=W1 from GLOBAL, Cn=4/Cm=8 ----
        float C1[4][8];
        {
            float4 bb = *(const float4*)(smem + OFF_B1 + nc1);
            float bv[4] = {bb.x, bb.y, bb.z, bb.w};
#pragma unroll
            for (int j = 0; j < 4; ++j)
#pragma unroll
                for (int m = 0; m < 8; ++m) C1[j][m] = bv[j];
#pragma unroll 4
            for (int k = 0; k < 64; ++k) {
                float4 a0 = *(const float4*)(hT + k * 132 + mA);
                float4 a1 = *(const float4*)(hT + k * 132 + 64 + mA);
                float av[8] = {a0.x, a0.y, a0.z, a0.w, a1.x, a1.y, a1.z, a1.w};
                float4 B = *(const float4*)(W1 + k * 64 + nc1);
                float bs[4] = {B.x, B.y, B.z, B.w};
#pragma unroll
                for (int j = 0; j < 4; ++j)
#pragma unroll
                    for (int m = 0; m < 8; ++m)
                        C1[j][m] = fmaf(av[m], bs[j], C1[j][m]);
            }
        }
        __syncthreads();  // all waves done READING h0

        // write h1 = gelu(C1) over hT
#pragma unroll
        for (int j = 0; j < 4; ++j) {
            float4 o0 = make_float4(gelu_f(C1[j][0]), gelu_f(C1[j][1]),
                                    gelu_f(C1[j][2]), gelu_f(C1[j][3]));
            float4 o1 = make_float4(gelu_f(C1[j][4]), gelu_f(C1[j][5]),
                                    gelu_f(C1[j][6]), gelu_f(C1[j][7]));
            *(float4*)(hT + (nc1 + j) * 132 + mA) = o0;
            *(float4*)(hT + (nc1 + j) * 132 + 64 + mA) = o1;
        }
        __syncthreads();  // h1 ready

        // ---- L2: [128,64] x [64,128], B=W2 from GLOBAL, Cn=8/Cm=8 ----
        {
            float C[8][8];
            {
                float4 b20 = *(const float4*)(smem + OFF_B2 + nc2);
                float4 b21 = *(const float4*)(smem + OFF_B2 + nc2 + 4);
                float bv[8] = {b20.x, b20.y, b20.z, b20.w, b21.x, b21.y, b21.z, b21.w};
#pragma unroll
                for (int j = 0; j < 8; ++j)
#pragma unroll
                    for (int m = 0; m < 8; ++m) C[j][m] = bv[j];
            }
#pragma unroll 2
            for (int k = 0; k < 64; ++k) {
                float4 a0 = *(const float4*)(hT + k * 132 + mA);
                float4 a1 = *(const float4*)(hT + k * 132 + 64 + mA);
                float av[8] = {a0.x, a0.y, a0.z, a0.w, a1.x, a1.y, a1.z, a1.w};
                float4 B0 = *(const float4*)(W2 + k * 128 + nc2);
                float4 B1 = *(const float4*)(W2 + k * 128 + nc2 + 4);
                float bs[8] = {B0.x, B0.y, B0.z, B0.w, B1.x, B1.y, B1.z, B1.w};
#pragma unroll
                for (int j = 0; j < 8; ++j)
#pragma unroll
                    for (int m = 0; m < 8; ++m)
                        C[j][m] = fmaf(av[m], bs[j], C[j][m]);
            }
            // epilogue: multiply by rndata[src], scatter-add into sacc
#pragma unroll
            for (int m = 0; m < 8; ++m) {
                int row = (m < 4) ? (mA + m) : (64 + mA + m - 4);
                int e = ebase + row;
                if (e < e1) {
                    int d = dsts[e], s = srcs[e];
                    float4 r0 = *(const float4*)(rndata + (size_t)s * 128 + nc2);
                    float4 r1 = *(const float4*)(rndata + (size_t)s * 128 + nc2 + 4);
                    float rs[8] = {r0.x, r0.y, r0.z, r0.w, r1.x, r1.y, r1.z, r1.w};
                    float* ac = &sacc[(d - q0) * 129 + nc2];
#pragma unroll
                    for (int j = 0; j < 8; ++j)
                        atomicAdd(&ac[j], C[j][m] * rs[j]);
                }
            }
        }
        __syncthreads();  // hT/einT safe to overwrite; sacc updates visible
    }
    __syncthreads();  // ntiles==0 path: sacc zero-init visible

    if (!FUSED_PROJ) {
        // write per-query mean to global agg (coalesced across c)
        for (int idx = tid; idx < QB * 128; idx += BLOCK) {
            int ql = idx >> 7, c = idx & 127;
            int q  = q0 + ql;
            if (q < qend) {
                float deg = (float)(start[q + 1] - start[q]);
                agg[(size_t)q * 128 + c] = sacc[ql * 129 + c] / fmaxf(deg, 1.f);
            }
        }
    } else {
        if (tid < QB) {
            int q = q0 + tid;
            if (q < nq) {
                float deg = (float)(start[q + 1] - start[q]);
                float inv = 1.0f / fmaxf(deg, 1.f);
                const float* aq = &sacc[tid * 129];
                float o0 = pb1[0], o1 = pb1[1], o2 = pb1[2], o3 = pb1[3];
#pragma unroll 1
                for (int jj = 0; jj < 256; jj += 8) {
                    float acc[8];
#pragma unroll
                    for (int u = 0; u < 8; ++u) acc[u] = pb0[jj + u];
#pragma unroll
                    for (int i = 0; i < 128; ++i) {
                        float av = aq[i] * inv;
#pragma unroll
                        for (int u = 0; u < 8; ++u)
                            acc[u] = fmaf(av, P0[i * 256 + jj + u], acc[u]);
                    }
#pragma unroll
                    for (int u = 0; u < 8; ++u) {
                        float h = gelu_f(acc[u]);
                        o0 = fmaf(h, P1[(jj + u) * 4 + 0], o0);
                        o1 = fmaf(h, P1[(jj + u) * 4 + 1], o1);
                        o2 = fmaf(h, P1[(jj + u) * 4 + 2], o2);
                        o3 = fmaf(h, P1[(jj + u) * 4 + 3], o3);
                    }
                }
                float4* o4 = (float4*)(out + (size_t)q * 4);
                *o4 = make_float4(o0, o1, o2, o3);
            }
        }
    }
}

// ---------- projection: plain r7/r9 kernel (proven ~270 us) ----------

__global__ __launch_bounds__(256) void proj_kernel(
    const float* __restrict__ agg,      // [NQ,128] mean
    const float* __restrict__ P0, const float* __restrict__ pb0,
    const float* __restrict__ P1, const float* __restrict__ pb1,
    float* __restrict__ out, int nq)
{
    int q = blockIdx.x * blockDim.x + threadIdx.x;
    if (q >= nq) return;

    float a[128];
    const float4* ag4 = (const float4*)(agg + (size_t)q * 128);
#pragma unroll
    for (int i = 0; i < 32; ++i) {
        float4 v = ag4[i];
        a[4 * i + 0] = v.x; a[4 * i + 1] = v.y;
        a[4 * i + 2] = v.z; a[4 * i + 3] = v.w;
    }

    float o0 = pb1[0], o1 = pb1[1], o2 = pb1[2], o3 = pb1[3];
#pragma unroll 1
    for (int jj = 0; jj < 256; jj += 8) {
        float acc[8];
#pragma unroll
        for (int u = 0; u < 8; ++u) acc[u] = pb0[jj + u];
#pragma unroll
        for (int i = 0; i < 128; ++i) {
            float av = a[i];
#pragma unroll
            for (int u = 0; u < 8; ++u)
                acc[u] = fmaf(av, P0[i * 256 + jj + u], acc[u]);
        }
#pragma unroll
        for (int u = 0; u < 8; ++u) {
            float h = gelu_f(acc[u]);
            o0 = fmaf(h, P1[(jj + u) * 4 + 0], o0);
            o1 = fmaf(h, P1[(jj + u) * 4 + 1], o1);
            o2 = fmaf(h, P1[(jj + u) * 4 + 2], o2);
            o3 = fmaf(h, P1[(jj + u) * 4 + 3], o3);
        }
    }
    float4* o4 = (float4*)(out + (size_t)q * 4);
    *o4 = make_float4(o0, o1, o2, o3);
}

extern "C" void kernel_launch(void* const* d_in, const int* in_sizes, int n_in,
                              void* d_out, int out_size, void* d_ws, size_t ws_size,
                              hipStream_t stream)
{
    const float* rndata = (const float*)d_in[0];
    const float* qpos   = (const float*)d_in[1];
    const float* lpos   = (const float*)d_in[2];
    const int*   dst    = (const int*)d_in[3];
    const int*   src    = (const int*)d_in[4];
    const float* W0  = (const float*)d_in[5];
    const float* b0  = (const float*)d_in[6];
    const float* W1  = (const float*)d_in[7];
    const float* b1  = (const float*)d_in[8];
    const float* W2  = (const float*)d_in[9];
    const float* b2  = (const float*)d_in[10];
    const float* P0  = (const float*)d_in[11];
    const float* pb0 = (const float*)d_in[12];
    const float* P1  = (const float*)d_in[13];
    const float* pb1 = (const float*)d_in[14];

    int nq = in_sizes[1] / 3;
    int E  = in_sizes[3];

    // ws layout: [agg nq*128 (path A)] [hist] [cursor] [start] [dsts] [srcs]
    size_t agg_bytes  = (size_t)nq * 128 * sizeof(float);
    size_t sort_bytes = 0;
    {
        size_t o = 0;
        o += ((size_t)nq * sizeof(int) + 15) & ~(size_t)15;
        o += ((size_t)nq * sizeof(int) + 15) & ~(size_t)15;
        o += ((size_t)(nq + 1) * sizeof(int) + 15) & ~(size_t)15;
        o += ((size_t)E * sizeof(int) + 15) & ~(size_t)15;
        o += ((size_t)E * sizeof(int) + 15) & ~(size_t)15;
        sort_bytes = o;
    }
    bool path_a = (agg_bytes + sort_bytes) <= ws_size;

    size_t off = path_a ? agg_bytes : 0;
    auto alloc = [&](size_t bytes) {
        void* p = (char*)d_ws + off;
        off += (bytes + 15) & ~(size_t)15;
        return p;
    };
    float* agg   = (float*)d_ws;  // path A only
    int* hist    = (int*)alloc((size_t)nq * sizeof(int));
    int* cursor  = (int*)alloc((size_t)nq * sizeof(int));
    int* start   = (int*)alloc((size_t)(nq + 1) * sizeof(int));
    int* dsts    = (int*)alloc((size_t)E * sizeof(int));
    int* srcs    = (int*)alloc((size_t)E * sizeof(int));

    size_t histpad = ((size_t)nq * sizeof(int) + 15) & ~(size_t)15;
    hipMemsetAsync(hist, 0, 2 * histpad, stream);

    hist_kernel<<<(E + 255) / 256, 256, 0, stream>>>(dst, hist, E);
    scan_kernel<<<1, 1024, 0, stream>>>(hist, start, nq);
    scatter_kernel<<<(E + 255) / 256, 256, 0, stream>>>(dst, src, start, cursor, dsts, srcs, E);

    constexpr int    QB   = 24;
    constexpr size_t SMEM = (size_t)(9880 + QB * 129) * 4;  // 51,904 B -> 3 blocks/CU
    int nb = (nq + QB - 1) / QB;

    if (path_a) {
        fused_kernel<QB, false><<<nb, BLOCK, SMEM, stream>>>(
            rndata, qpos, lpos, dsts, srcs, start,
            W0, b0, W1, b1, W2, b2, P0, pb0, P1, pb1, agg, nullptr, nq);
        proj_kernel<<<(nq + 255) / 256, 256, 0, stream>>>(
            agg, P0, pb0, P1, pb1, (float*)d_out, nq);
    } else {
        fused_kernel<QB, true><<<nb, BLOCK, SMEM, stream>>>(
            rndata, qpos, lpos, dsts, srcs, start,
            W0, b0, W1, b1, W2, b2, P0, pb0, P1, pb1, nullptr, (float*)d_out, nq);
    }
}

// Round 14
// 1571.806 us; speedup vs baseline: 1.7076x; 1.0017x over previous
//
#include <hip/hip_runtime.h>

// GNODecoder round 14: r13's Cm=8 body was right but register-starved --
// VGPR_Count=60 vs the ~105 needed (C[8][8] spilled to L2-resident scratch).
// Audit of all rounds: the allocator only grants >=128 VGPR when
// __launch_bounds__ has the SECOND argument (min waves/EU): (256,2) gave
// 176/128 in r3-r6; bare (N) or 512/1024-thread blocks gave 40-64.
// Single change: __launch_bounds__(256, 2) on fused_kernel.

#define BLOCK 256

// LDS float offsets
#define OFF_W0   0      // [6][64] = 384
#define OFF_B0   384    // [64]
#define OFF_B1   448    // [64]
#define OFF_B2   512    // [128]
#define OFF_EIN  640    // [6][132] = 792
#define OFF_HT   1432   // [64][132] = 8448 (h0 then h1)
#define OFF_SACC 9880   // [QB*129]

__device__ __forceinline__ float gelu_f(float x) {
    // jax.nn.gelu default (approximate=True, tanh form)
    float x3 = x * x * x;
    float t  = 0.7978845608028654f * fmaf(0.044715f, x3, x);
    float e  = __expf(2.0f * t);
    float r  = __builtin_amdgcn_rcpf(e + 1.0f);
    return 0.5f * x * (1.0f + (1.0f - 2.0f * r));
}

// ---------- sort machinery (proven) ----------

__global__ void hist_kernel(const int* __restrict__ dst, int* __restrict__ hist, int E) {
    int e = blockIdx.x * blockDim.x + threadIdx.x;
    if (e < E) atomicAdd(&hist[dst[e]], 1);
}

__global__ __launch_bounds__(1024) void scan_kernel(const int* __restrict__ hist,
                                                    int* __restrict__ start, int n) {
    __shared__ int wsum[16];
    __shared__ int woff[16];
    int tid = threadIdx.x;
    int lane = tid & 63, wid = tid >> 6;
    int carry = 0;  // meaningful on tid 0 only
    for (int base = 0; base < n; base += 1024) {
        int i = base + tid;
        int v = (i < n) ? hist[i] : 0;
        int incl = v;
#pragma unroll
        for (int off = 1; off < 64; off <<= 1) {
            int t = __shfl_up(incl, off, 64);
            if (lane >= off) incl += t;
        }
        if (lane == 63) wsum[wid] = incl;
        __syncthreads();
        if (tid == 0) {
            int acc = carry;
#pragma unroll
            for (int w = 0; w < 16; ++w) { woff[w] = acc; acc += wsum[w]; }
            carry = acc;
        }
        __syncthreads();
        if (i < n) start[i] = woff[wid] + incl - v;
        __syncthreads();
    }
    if (threadIdx.x == 0) start[n] = carry;
}

__global__ void scatter_kernel(const int* __restrict__ dst, const int* __restrict__ src,
                               const int* __restrict__ start, int* __restrict__ cursor,
                               int* __restrict__ dsts, int* __restrict__ srcs, int E) {
    int e = blockIdx.x * blockDim.x + threadIdx.x;
    if (e >= E) return;
    int d = dst[e];
    int pos = start[d] + atomicAdd(&cursor[d], 1);
    dsts[pos] = d;
    srcs[pos] = src[e];
}

// ---------- fused: M=128 tiled GEMM, Cm=8 split-M, weights-from-global ----------

template <int QB, bool FUSED_PROJ>
__global__ __launch_bounds__(BLOCK, 2) void fused_kernel(
    const float* __restrict__ rndata,   // [NL,128]
    const float* __restrict__ qpos,     // [NQ,3]
    const float* __restrict__ lpos,     // [NL,3]
    const int*   __restrict__ dsts,     // [E] sorted by dst
    const int*   __restrict__ srcs,     // [E]
    const int*   __restrict__ start,    // [NQ+1]
    const float* __restrict__ W0, const float* __restrict__ b0,
    const float* __restrict__ W1, const float* __restrict__ b1,
    const float* __restrict__ W2, const float* __restrict__ b2,
    const float* __restrict__ P0, const float* __restrict__ pb0,
    const float* __restrict__ P1, const float* __restrict__ pb1,
    float* __restrict__ agg,            // [NQ,128] mean (path A)
    float* __restrict__ out,            // [NQ,4]   (FUSED_PROJ)
    int nq)
{
    extern __shared__ float smem[];
    const int tid = threadIdx.x;

    // ---- stage small weights (W0 + biases); W1/W2 stay in global/L1 ----
    if (tid < 96)       ((float4*)(smem + OFF_W0))[tid]       = ((const float4*)W0)[tid];
    else if (tid < 112) ((float4*)(smem + OFF_B0))[tid - 96]  = ((const float4*)b0)[tid - 96];
    else if (tid < 128) ((float4*)(smem + OFF_B1))[tid - 112] = ((const float4*)b1)[tid - 112];
    else if (tid < 160) ((float4*)(smem + OFF_B2))[tid - 128] = ((const float4*)b2)[tid - 128];
    for (int i = tid; i < QB * 129; i += BLOCK) smem[OFF_SACC + i] = 0.f;

    float* einT = smem + OFF_EIN;   // [6][132]
    float* hT   = smem + OFF_HT;    // [64][132]
    float* sacc = smem + OFF_SACC;  // [QB][129]

    const int q0   = blockIdx.x * QB;
    const int qend = min(q0 + QB, nq);
    const int e0 = start[q0], e1 = start[qend];
    const int ntiles = (e1 - e0 + 127) >> 7;

    const int w = tid >> 6, lane = tid & 63;
    const int mg = lane & 15, ng = lane >> 4;
    const int mA  = mg * 4;              // rows mA..mA+3 and 64+mA..64+mA+3
    const int nc1 = w * 16 + ng * 4;     // L0/L1 n-base (N=64)
    const int nc2 = w * 32 + ng * 8;     // L2 n-base (N=128)

    for (int t = 0; t < ntiles; ++t) {
        const int ebase = e0 + (t << 7);

        // ---- gather einT (threads 0..127, one edge each) ----
        if (tid < 128) {
            int e = ebase + tid;
            if (e < e1) {
                int d = dsts[e], s = srcs[e];
                einT[0 * 132 + tid] = qpos[d * 3 + 0];
                einT[1 * 132 + tid] = qpos[d * 3 + 1];
                einT[2 * 132 + tid] = qpos[d * 3 + 2];
                einT[3 * 132 + tid] = lpos[s * 3 + 0];
                einT[4 * 132 + tid] = lpos[s * 3 + 1];
                einT[5 * 132 + tid] = lpos[s * 3 + 2];
            } else {
#pragma unroll
                for (int c = 0; c < 6; ++c) einT[c * 132 + tid] = 0.f;
            }
        }
        __syncthreads();  // einT ready (first iter: staging too)

        // ---- L0: [128,6] x [6,64] -> hT (h0), B from LDS, Cn=4/Cm=8 ----
        {
            float C[4][8];
            float4 bb = *(const float4*)(smem + OFF_B0 + nc1);
            float bv[4] = {bb.x, bb.y, bb.z, bb.w};
#pragma unroll
            for (int j = 0; j < 4; ++j)
#pragma unroll
                for (int m = 0; m < 8; ++m) C[j][m] = bv[j];
#pragma unroll
            for (int k = 0; k < 6; ++k) {
                float4 a0 = *(const float4*)(einT + k * 132 + mA);
                float4 a1 = *(const float4*)(einT + k * 132 + 64 + mA);
                float av[8] = {a0.x, a0.y, a0.z, a0.w, a1.x, a1.y, a1.z, a1.w};
                float4 B = *(const float4*)(smem + OFF_W0 + k * 64 + nc1);
                float bs[4] = {B.x, B.y, B.z, B.w};
#pragma unroll
                for (int j = 0; j < 4; ++j)
#pragma unroll
                    for (int m = 0; m < 8; ++m)
                        C[j][m] = fmaf(av[m], bs[j], C[j][m]);
            }
#pragma unroll
            for (int j = 0; j < 4; ++j) {
                float4 o0 = make_float4(gelu_f(C[j][0]), gelu_f(C[j][1]),
                                        gelu_f(C[j][2]), gelu_f(C[j][3]));
                float4 o1 = make_float4(gelu_f(C[j][4]), gelu_f(C[j][5]),
                                        gelu_f(C[j][6]), gelu_f(C[j][7]));
                *(float4*)(hT + (nc1 + j) * 132 + mA) = o0;
                *(float4*)(hT + (nc1 + j) * 132 + 64 + mA) = o1;
            }
        }
        __syncthreads();  // h0 ready

        // ---- L1: [128,64] x [64,64], B=W1 from GLOBAL, Cn=4/Cm=8 ----
        float C1[4][8];
        {
            float4 bb = *(const float4*)(smem + OFF_B1 + nc1);
            float bv[4] = {bb.x, bb.y, bb.z, bb.w};
#pragma unroll
            for (int j = 0; j < 4; ++j)
#pragma unroll
                for (int m = 0; m < 8; ++m) C1[j][m] = bv[j];
#pragma unroll 4
            for (int k = 0; k < 64; ++k) {
                float4 a0 = *(const float4*)(hT + k * 132 + mA);
                float4 a1 = *(const float4*)(hT + k * 132 + 64 + mA);
                float av[8] = {a0.x, a0.y, a0.z, a0.w, a1.x, a1.y, a1.z, a1.w};
                float4 B = *(const float4*)(W1 + k * 64 + nc1);
                float bs[4] = {B.x, B.y, B.z, B.w};
#pragma unroll
                for (int j = 0; j < 4; ++j)
#pragma unroll
                    for (int m = 0; m < 8; ++m)
                        C1[j][m] = fmaf(av[m], bs[j], C1[j][m]);
            }
        }
        __syncthreads();  // all waves done READING h0

        // write h1 = gelu(C1) over hT
#pragma unroll
        for (int j = 0; j < 4; ++j) {
            float4 o0 = make_float4(gelu_f(C1[j][0]), gelu_f(C1[j][1]),
                                    gelu_f(C1[j][2]), gelu_f(C1[j][3]));
            float4 o1 = make_float4(gelu_f(C1[j][4]), gelu_f(C1[j][5]),
                                    gelu_f(C1[j][6]), gelu_f(C1[j][7]));
            *(float4*)(hT + (nc1 + j) * 132 + mA) = o0;
            *(float4*)(hT + (nc1 + j) * 132 + 64 + mA) = o1;
        }
        __syncthreads();  // h1 ready

        // ---- L2: [128,64] x [64,128], B=W2 from GLOBAL, Cn=8/Cm=8 ----
        {
            float C[8][8];
            {
                float4 b20 = *(const float4*)(smem + OFF_B2 + nc2);
                float4 b21 = *(const float4*)(smem + OFF_B2 + nc2 + 4);
                float bv[8] = {b20.x, b20.y, b20.z, b20.w, b21.x, b21.y, b21.z, b21.w};
#pragma unroll
                for (int j = 0; j < 8; ++j)
#pragma unroll
                    for (int m = 0; m < 8; ++m) C[j][m] = bv[j];
            }
#pragma unroll 2
            for (int k = 0; k < 64; ++k) {
                float4 a0 = *(const float4*)(hT + k * 132 + mA);
                float4 a1 = *(const float4*)(hT + k * 132 + 64 + mA);
                float av[8] = {a0.x, a0.y, a0.z, a0.w, a1.x, a1.y, a1.z, a1.w};
                float4 B0 = *(const float4*)(W2 + k * 128 + nc2);
                float4 B1 = *(const float4*)(W2 + k * 128 + nc2 + 4);
                float bs[8] = {B0.x, B0.y, B0.z, B0.w, B1.x, B1.y, B1.z, B1.w};
#pragma unroll
                for (int j = 0; j < 8; ++j)
#pragma unroll
                    for (int m = 0; m < 8; ++m)
                        C[j][m] = fmaf(av[m], bs[j], C[j][m]);
            }
            // epilogue: multiply by rndata[src], scatter-add into sacc
#pragma unroll
            for (int m = 0; m < 8; ++m) {
                int row = (m < 4) ? (mA + m) : (64 + mA + m - 4);
                int e = ebase + row;
                if (e < e1) {
                    int d = dsts[e], s = srcs[e];
                    float4 r0 = *(const float4*)(rndata + (size_t)s * 128 + nc2);
                    float4 r1 = *(const float4*)(rndata + (size_t)s * 128 + nc2 + 4);
                    float rs[8] = {r0.x, r0.y, r0.z, r0.w, r1.x, r1.y, r1.z, r1.w};
                    float* ac = &sacc[(d - q0) * 129 + nc2];
#pragma unroll
                    for (int j = 0; j < 8; ++j)
                        atomicAdd(&ac[j], C[j][m] * rs[j]);
                }
            }
        }
        __syncthreads();  // hT/einT safe to overwrite; sacc updates visible
    }
    __syncthreads();  // ntiles==0 path: sacc zero-init visible

    if (!FUSED_PROJ) {
        // write per-query mean to global agg (coalesced across c)
        for (int idx = tid; idx < QB * 128; idx += BLOCK) {
            int ql = idx >> 7, c = idx & 127;
            int q  = q0 + ql;
            if (q < qend) {
                float deg = (float)(start[q + 1] - start[q]);
                agg[(size_t)q * 128 + c] = sacc[ql * 129 + c] / fmaxf(deg, 1.f);
            }
        }
    } else {
        if (tid < QB) {
            int q = q0 + tid;
            if (q < nq) {
                float deg = (float)(start[q + 1] - start[q]);
                float inv = 1.0f / fmaxf(deg, 1.f);
                const float* aq = &sacc[tid * 129];
                float o0 = pb1[0], o1 = pb1[1], o2 = pb1[2], o3 = pb1[3];
#pragma unroll 1
                for (int jj = 0; jj < 256; jj += 8) {
                    float acc[8];
#pragma unroll
                    for (int u = 0; u < 8; ++u) acc[u] = pb0[jj + u];
#pragma unroll
                    for (int i = 0; i < 128; ++i) {
                        float av = aq[i] * inv;
#pragma unroll
                        for (int u = 0; u < 8; ++u)
                            acc[u] = fmaf(av, P0[i * 256 + jj + u], acc[u]);
                    }
#pragma unroll
                    for (int u = 0; u < 8; ++u) {
                        float h = gelu_f(acc[u]);
                        o0 = fmaf(h, P1[(jj + u) * 4 + 0], o0);
                        o1 = fmaf(h, P1[(jj + u) * 4 + 1], o1);
                        o2 = fmaf(h, P1[(jj + u) * 4 + 2], o2);
                        o3 = fmaf(h, P1[(jj + u) * 4 + 3], o3);
                    }
                }
                float4* o4 = (float4*)(out + (size_t)q * 4);
                *o4 = make_float4(o0, o1, o2, o3);
            }
        }
    }
}

// ---------- projection: plain r7/r9 kernel (proven ~270 us) ----------

__global__ __launch_bounds__(256) void proj_kernel(
    const float* __restrict__ agg,      // [NQ,128] mean
    const float* __restrict__ P0, const float* __restrict__ pb0,
    const float* __restrict__ P1, const float* __restrict__ pb1,
    float* __restrict__ out, int nq)
{
    int q = blockIdx.x * blockDim.x + threadIdx.x;
    if (q >= nq) return;

    float a[128];
    const float4* ag4 = (const float4*)(agg + (size_t)q * 128);
#pragma unroll
    for (int i = 0; i < 32; ++i) {
        float4 v = ag4[i];
        a[4 * i + 0] = v.x; a[4 * i + 1] = v.y;
        a[4 * i + 2] = v.z; a[4 * i + 3] = v.w;
    }

    float o0 = pb1[0], o1 = pb1[1], o2 = pb1[2], o3 = pb1[3];
#pragma unroll 1
    for (int jj = 0; jj < 256; jj += 8) {
        float acc[8];
#pragma unroll
        for (int u = 0; u < 8; ++u) acc[u] = pb0[jj + u];
#pragma unroll
        for (int i = 0; i < 128; ++i) {
            float av = a[i];
#pragma unroll
            for (int u = 0; u < 8; ++u)
                acc[u] = fmaf(av, P0[i * 256 + jj + u], acc[u]);
        }
#pragma unroll
        for (int u = 0; u < 8; ++u) {
            float h = gelu_f(acc[u]);
            o0 = fmaf(h, P1[(jj + u) * 4 + 0], o0);
            o1 = fmaf(h, P1[(jj + u) * 4 + 1], o1);
            o2 = fmaf(h, P1[(jj + u) * 4 + 2], o2);
            o3 = fmaf(h, P1[(jj + u) * 4 + 3], o3);
        }
    }
    float4* o4 = (float4*)(out + (size_t)q * 4);
    *o4 = make_float4(o0, o1, o2, o3);
}

extern "C" void kernel_launch(void* const* d_in, const int* in_sizes, int n_in,
                              void* d_out, int out_size, void* d_ws, size_t ws_size,
                              hipStream_t stream)
{
    const float* rndata = (const float*)d_in[0];
    const float* qpos   = (const float*)d_in[1];
    const float* lpos   = (const float*)d_in[2];
    const int*   dst    = (const int*)d_in[3];
    const int*   src    = (const int*)d_in[4];
    const float* W0  = (const float*)d_in[5];
    const float* b0  = (const float*)d_in[6];
    const float* W1  = (const float*)d_in[7];
    const float* b1  = (const float*)d_in[8];
    const float* W2  = (const float*)d_in[9];
    const float* b2  = (const float*)d_in[10];
    const float* P0  = (const float*)d_in[11];
    const float* pb0 = (const float*)d_in[12];
    const float* P1  = (const float*)d_in[13];
    const float* pb1 = (const float*)d_in[14];

    int nq = in_sizes[1] / 3;
    int E  = in_sizes[3];

    // ws layout: [agg nq*128 (path A)] [hist] [cursor] [start] [dsts] [srcs]
    size_t agg_bytes  = (size_t)nq * 128 * sizeof(float);
    size_t sort_bytes = 0;
    {
        size_t o = 0;
        o += ((size_t)nq * sizeof(int) + 15) & ~(size_t)15;
        o += ((size_t)nq * sizeof(int) + 15) & ~(size_t)15;
        o += ((size_t)(nq + 1) * sizeof(int) + 15) & ~(size_t)15;
        o += ((size_t)E * sizeof(int) + 15) & ~(size_t)15;
        o += ((size_t)E * sizeof(int) + 15) & ~(size_t)15;
        sort_bytes = o;
    }
    bool path_a = (agg_bytes + sort_bytes) <= ws_size;

    size_t off = path_a ? agg_bytes : 0;
    auto alloc = [&](size_t bytes) {
        void* p = (char*)d_ws + off;
        off += (bytes + 15) & ~(size_t)15;
        return p;
    };
    float* agg   = (float*)d_ws;  // path A only
    int* hist    = (int*)alloc((size_t)nq * sizeof(int));
    int* cursor  = (int*)alloc((size_t)nq * sizeof(int));
    int* start   = (int*)alloc((size_t)(nq + 1) * sizeof(int));
    int* dsts    = (int*)alloc((size_t)E * sizeof(int));
    int* srcs    = (int*)alloc((size_t)E * sizeof(int));

    size_t histpad = ((size_t)nq * sizeof(int) + 15) & ~(size_t)15;
    hipMemsetAsync(hist, 0, 2 * histpad, stream);

    hist_kernel<<<(E + 255) / 256, 256, 0, stream>>>(dst, hist, E);
    scan_kernel<<<1, 1024, 0, stream>>>(hist, start, nq);
    scatter_kernel<<<(E + 255) / 256, 256, 0, stream>>>(dst, src, start, cursor, dsts, srcs, E);

    constexpr int    QB   = 24;
    constexpr size_t SMEM = (size_t)(9880 + QB * 129) * 4;  // 51,904 B
    int nb = (nq + QB - 1) / QB;

    if (path_a) {
        fused_kernel<QB, false><<<nb, BLOCK, SMEM, stream>>>(
            rndata, qpos, lpos, dsts, srcs, start,
            W0, b0, W1, b1, W2, b2, P0, pb0, P1, pb1, agg, nullptr, nq);
        proj_kernel<<<(nq + 255) / 256, 256, 0, stream>>>(
            agg, P0, pb0, P1, pb1, (float*)d_out, nq);
    } else {
        fused_kernel<QB, true><<<nb, BLOCK, SMEM, stream>>>(
            rndata, qpos, lpos, dsts, srcs, start,
            W0, b0, W1, b1, W2, b2, P0, pb0, P1, pb1, nullptr, (float*)d_out, nq);
    }
}